// Round 9
// baseline (328.985 us; speedup 1.0000x reference)
//
#include <hip/hip_runtime.h>
#include <hip/hip_bf16.h>

typedef __bf16 bf16x8 __attribute__((ext_vector_type(8)));
typedef float floatx4 __attribute__((ext_vector_type(4)));

#define DIM   2048
#define SEQ   2048
#define BATCH 2
#define NKV   8
#define NGRP  4
#define HDIM  64
#define KVDIM (NKV * HDIM)   // 512
#define QKVD  3072           // fused q|k|v projection width

__device__ __forceinline__ ushort f2bf(float f) {          // RNE
  union { float f; unsigned u; } x; x.f = f;
  return (ushort)((x.u + 0x7fffu + ((x.u >> 16) & 1u)) >> 16);
}
// pack two floats -> two bf16 in one u32 (round-half-up, bit trick)
__device__ __forceinline__ unsigned pack_bf2(float a, float b) {
  union { float f; unsigned u; } x, y; x.f = a; y.f = b;
  unsigned ua = x.u + 0x8000u, ub = y.u + 0x8000u;
  return __builtin_amdgcn_perm(ub, ua, 0x07060302);
}
// pack two floats -> two bf16 in one u32 via v_cvt_pk_bf16_f32 (RNE, 1 instr)
__device__ __forceinline__ unsigned pack_bf2_rn(float a, float b) {
  __hip_bfloat162 h = __float22bfloat162_rn(make_float2(a, b));
  union { __hip_bfloat162 h; unsigned u; } cv; cv.h = h; return cv.u;
}

typedef const __attribute__((address_space(1))) void* gas_t;
typedef __attribute__((address_space(3))) void* las_t;
__device__ __forceinline__ void gload_lds16(const ushort* g, ushort* l) {
  __builtin_amdgcn_global_load_lds((gas_t)g, (las_t)l, 16, 0, 0);
}

// ------- x fp32 -> bf16 bulk convert (fallback body) -------------------------
__global__ __launch_bounds__(256) void cvt_f2b(
    const float* __restrict__ in, ushort* __restrict__ out)
{
  int i = blockIdx.x * 256 + threadIdx.x;     // one uint4 (8 bf16) per thread
  const float4* p = (const float4*)in + (size_t)i * 2;
  float4 f0 = p[0], f1 = p[1];
  uint4 v;
  v.x = pack_bf2(f0.x, f0.y); v.y = pack_bf2(f0.z, f0.w);
  v.z = pack_bf2(f1.x, f1.y); v.w = pack_bf2(f1.z, f1.w);
  ((uint4*)out)[i] = v;
}

// ------- transpose + convert: fp32 [R,C] -> bf16 [C,R] (weights) ------------
__global__ __launch_bounds__(256) void transpose_f2b(
    const float* __restrict__ in, ushort* __restrict__ out, int R, int C)
{
  __shared__ ushort tileT[64][72];
  int tr = blockIdx.y * 64;
  int tc = blockIdx.x * 64;
  int row = threadIdx.x >> 2;
  int c16 = (threadIdx.x & 3) * 16;

  ushort arr[16];
  const float* src = in + (size_t)(tr + row) * C + tc + c16;
#pragma unroll
  for (int q = 0; q < 4; ++q) {
    float4 f = *(const float4*)(src + q * 4);
    arr[q * 4 + 0] = f2bf(f.x); arr[q * 4 + 1] = f2bf(f.y);
    arr[q * 4 + 2] = f2bf(f.z); arr[q * 4 + 3] = f2bf(f.w);
  }
  int rot = row & 15;
#pragma unroll
  for (int j = 0; j < 16; ++j) {
    int i2 = (j + rot) & 15;
    tileT[c16 + i2][row] = arr[i2];
  }
  __syncthreads();
  ushort* dst = out + (size_t)(tc + row) * R + tr + c16;
  *(uint4*)dst       = *(const uint4*)&tileT[row][c16];
  *(uint4*)(dst + 8) = *(const uint4*)&tileT[row][c16 + 8];
}

// ------- fused prep: x convert (blocks 0..4095) + 4 weight transposes -------
__global__ __launch_bounds__(256) void prep_all(
    const float* __restrict__ x,
    const float* __restrict__ Wq, const float* __restrict__ Wk,
    const float* __restrict__ Wv, const float* __restrict__ Wo,
    ushort* __restrict__ xb, ushort* __restrict__ WqkvT, ushort* __restrict__ WoT)
{
  __shared__ ushort tileT[64][72];
  int bid = blockIdx.x;
  if (bid < 4096) {                 // ---- cvt: x fp32 -> bf16 ----
    int i = bid * 256 + threadIdx.x;
    const float4* p = (const float4*)x + (size_t)i * 2;
    float4 f0 = p[0], f1 = p[1];
    uint4 v;
    v.x = pack_bf2(f0.x, f0.y); v.y = pack_bf2(f0.z, f0.w);
    v.z = pack_bf2(f1.x, f1.y); v.w = pack_bf2(f1.z, f1.w);
    ((uint4*)xb)[i] = v;
    return;
  }
  // ---- weight transposes ----
  const size_t Mi = 1024 * 1024;
  int id = bid - 4096;
  const float* in; ushort* out; int C;
  if (id < 1024)      { in = Wq; out = WqkvT;          C = 2048; }
  else if (id < 1280) { in = Wk; out = WqkvT + 4 * Mi; C = 512;  id -= 1024; }
  else if (id < 1536) { in = Wv; out = WqkvT + 5 * Mi; C = 512;  id -= 1280; }
  else                { in = Wo; out = WoT;            C = 2048; id -= 1536; }
  const int R = 2048;
  int nbx = C / 64;
  int tr = (id / nbx) * 64;
  int tc = (id % nbx) * 64;
  int row = threadIdx.x >> 2;
  int c16 = (threadIdx.x & 3) * 16;

  ushort arr[16];
  const float* src = in + (size_t)(tr + row) * C + tc + c16;
#pragma unroll
  for (int q = 0; q < 4; ++q) {
    float4 f = *(const float4*)(src + q * 4);
    arr[q * 4 + 0] = f2bf(f.x); arr[q * 4 + 1] = f2bf(f.y);
    arr[q * 4 + 2] = f2bf(f.z); arr[q * 4 + 3] = f2bf(f.w);
  }
  int rot = row & 15;
#pragma unroll
  for (int j = 0; j < 16; ++j) {
    int i2 = (j + rot) & 15;
    tileT[c16 + i2][row] = arr[i2];
  }
  __syncthreads();
  ushort* dst = out + (size_t)(tc + row) * R + tr + c16;
  *(uint4*)dst       = *(const uint4*)&tileT[row][c16];
  *(uint4*)(dst + 8) = *(const uint4*)&tileT[row][c16 + 8];
}

// ------- transpose bf16 [R,C] (strided rows) -> bf16 [C,R], batched ---------
__global__ __launch_bounds__(256) void transpose_b2b(
    const ushort* __restrict__ in, ushort* __restrict__ out,
    int R, int C, int in_stride, size_t in_batch, size_t out_batch)
{
  __shared__ ushort tileT[64][72];
  in  += (size_t)blockIdx.z * in_batch;
  out += (size_t)blockIdx.z * out_batch;
  int tr = blockIdx.y * 64;
  int tc = blockIdx.x * 64;
  int row = threadIdx.x >> 2;
  int c16 = (threadIdx.x & 3) * 16;

  ushort arr[16];
  const ushort* src = in + (size_t)(tr + row) * in_stride + tc + c16;
  *(uint4*)&arr[0] = *(const uint4*)src;
  *(uint4*)&arr[8] = *(const uint4*)(src + 8);
  int rot = row & 15;
#pragma unroll
  for (int j = 0; j < 16; ++j) {
    int i2 = (j + rot) & 15;
    tileT[c16 + i2][row] = arr[i2];
  }
  __syncthreads();
  ushort* dst = out + (size_t)(tc + row) * R + tr + c16;
  *(uint4*)dst       = *(const uint4*)&tileT[row][c16];
  *(uint4*)(dst + 8) = *(const uint4*)&tileT[row][c16 + 8];
}

// ------- 3-deep counted-vmcnt GEMM: C[M,N] = A[M,K] @ Bt[N,K]^T, bf16 -------
// 128x128 tile, BK=32, TRIPLE-buffered LDS (48 KB). Per K-step:
//   s_waitcnt vmcnt(4)   -- own tile-t loads landed (t+1's 4 stay in flight)
//   s_barrier            -- wait-BEFORE-barrier: all waves' t-loads landed
//   issue stage(t+2)     -- loads get 2 compute phases + barrier to land
//   compute tile t
// WAR safe: buf((t+2)%3) last read in compute(t-1), whose ds_reads completed
// (lgkm-waited before MFMA use) before this wave reached barrier_t.
// XCD-aware block swizzle (bijective when nwg%8==0).
template<bool CF32>
__global__ __launch_bounds__(256) void gemm_lds(
    const ushort* __restrict__ A, const ushort* __restrict__ Bt,
    void* __restrict__ Cv, int M, int N, int K)
{
  __shared__ ushort As[3][128 * 32];   // 8 KB per buf
  __shared__ ushort Bs[3][128 * 32];
  int tid  = threadIdx.x;

  int gx  = gridDim.x;
  int nwg = gx * gridDim.y;
  int lin = blockIdx.y * gx + blockIdx.x;
  if ((nwg & 7) == 0) {                 // XCD swizzle, bijective
    int cpx = nwg >> 3;
    lin = (lin & 7) * cpx + (lin >> 3);
  }
  int bm = (lin / gx) * 128;
  int bn = (lin % gx) * 128;

  int wv   = tid >> 6;
  int ln   = tid & 63;
  int wr   = (wv >> 1) * 64;
  int wc   = (wv & 1) * 64;
  int l15  = ln & 15;
  int quad = ln >> 4;

  // staging: wave wv fills rows 32wv..32wv+31; issue i covers rows +16i.
  // lane: row = 32wv+16i+(ln>>2), col = (ln&3)*8 ; LDS chunk = base + ln*16B
  int r4 = ln >> 2;
  int c8 = (ln & 3) * 8;
  const ushort* Ag0 = A  + (size_t)(bm + 32 * wv +      r4) * K + c8;
  const ushort* Ag1 = A  + (size_t)(bm + 32 * wv + 16 + r4) * K + c8;
  const ushort* Bg0 = Bt + (size_t)(bn + 32 * wv +      r4) * K + c8;
  const ushort* Bg1 = Bt + (size_t)(bn + 32 * wv + 16 + r4) * K + c8;
  int st0 = 1024 * wv +       ln * 8;
  int st1 = 1024 * wv + 512 + ln * 8;

  floatx4 acc[4][4];
#pragma unroll
  for (int i = 0; i < 4; ++i)
#pragma unroll
    for (int j = 0; j < 4; ++j) acc[i][j] = floatx4{0,0,0,0};

  const int NT = K >> 5;               // K-steps

  // prologue: stage tiles 0 and 1 into bufs 0 and 1 (8 loads in flight)
  gload_lds16(Ag0, &As[0][0] + st0);
  gload_lds16(Ag1, &As[0][0] + st1);
  gload_lds16(Bg0, &Bs[0][0] + st0);
  gload_lds16(Bg1, &Bs[0][0] + st1);
  Ag0 += 32; Ag1 += 32; Bg0 += 32; Bg1 += 32;
  gload_lds16(Ag0, &As[1][0] + st0);
  gload_lds16(Ag1, &As[1][0] + st1);
  gload_lds16(Bg0, &Bs[1][0] + st0);
  gload_lds16(Bg1, &Bs[1][0] + st1);
  Ag0 += 32; Ag1 += 32; Bg0 += 32; Bg1 += 32;

  int cur = 0;                         // buffer of tile t
  int stg = 2;                         // buffer of tile t+2
  for (int t = 0; t < NT; ++t) {
    if (t + 1 < NT) asm volatile("s_waitcnt vmcnt(4)" ::: "memory");
    else            asm volatile("s_waitcnt vmcnt(0)" ::: "memory");
    __builtin_amdgcn_s_barrier();      // raw barrier: no full drain

    if (t + 2 < NT) {                  // stage tile t+2 into buf stg
      ushort* Ad = &As[stg][0];
      ushort* Bd = &Bs[stg][0];
      gload_lds16(Ag0, Ad + st0);
      gload_lds16(Ag1, Ad + st1);
      gload_lds16(Bg0, Bd + st0);
      gload_lds16(Bg1, Bd + st1);
      Ag0 += 32; Ag1 += 32; Bg0 += 32; Bg1 += 32;
    }

    bf16x8 a[4], b[4];
#pragma unroll
    for (int q = 0; q < 4; ++q) {
      a[q] = *(const bf16x8*)&As[cur][(wr + q * 16 + l15) * 32 + quad * 8];
      b[q] = *(const bf16x8*)&Bs[cur][(wc + q * 16 + l15) * 32 + quad * 8];
    }
#pragma unroll
    for (int mt = 0; mt < 4; ++mt)
#pragma unroll
      for (int nt = 0; nt < 4; ++nt)
        acc[mt][nt] = __builtin_amdgcn_mfma_f32_16x16x32_bf16(a[mt], b[nt], acc[mt][nt], 0, 0, 0);

    cur = (cur == 2) ? 0 : cur + 1;
    stg = (stg == 2) ? 0 : stg + 1;
  }

#pragma unroll
  for (int mt = 0; mt < 4; ++mt)
#pragma unroll
    for (int nt = 0; nt < 4; ++nt)
#pragma unroll
      for (int r = 0; r < 4; ++r) {
        size_t idx = (size_t)(bm + wr + mt * 16 + quad * 4 + r) * N
                     + bn + wc + nt * 16 + l15;
        if (CF32) ((float*)Cv)[idx] = acc[mt][nt][r];
        else      ((ushort*)Cv)[idx] = f2bf(acc[mt][nt][r]);
      }
}

// ------- legacy GEMMs (fallback path) ---------------------------------------
#define BM 64
#define BN 64
#define BK 32
#define KP 40

template<bool AF32, bool CF32>
__global__ __launch_bounds__(256) void gemm_abt(
    const void* __restrict__ Av, const ushort* __restrict__ Bt,
    void* __restrict__ Cv, int M, int N, int K)
{
  __shared__ ushort As[BM * KP];
  __shared__ ushort Bs[BN * KP];
  int tid  = threadIdx.x;
  int bm   = blockIdx.y * BM;
  int bn   = blockIdx.x * BN;
  int wave = tid >> 6;
  int lane = tid & 63;
  int wr   = (wave >> 1) * 32;
  int wc   = (wave & 1) * 32;
  int l15  = lane & 15;
  int k8   = (lane >> 4) * 8;

  int srow = tid >> 2;
  int scol = (tid & 3) * 8;

  const float*  Af = (const float*)Av  + (size_t)(bm + srow) * K + scol;
  const ushort* Ah = (const ushort*)Av + (size_t)(bm + srow) * K + scol;
  const ushort* Bp = Bt + (size_t)(bn + srow) * K + scol;

  floatx4 acc00 = {0,0,0,0}, acc01 = {0,0,0,0}, acc10 = {0,0,0,0}, acc11 = {0,0,0,0};

  uint4 av, bv;
  if (AF32) {
    float4 f0 = *(const float4*)Af;
    float4 f1 = *(const float4*)(Af + 4);
    av.x = pack_bf2(f0.x, f0.y); av.y = pack_bf2(f0.z, f0.w);
    av.z = pack_bf2(f1.x, f1.y); av.w = pack_bf2(f1.z, f1.w);
  } else {
    av = *(const uint4*)Ah;
  }
  bv = *(const uint4*)Bp;

  for (int k0 = 0; k0 < K; k0 += BK) {
    __syncthreads();
    *(uint4*)&As[srow * KP + scol] = av;
    *(uint4*)&Bs[srow * KP + scol] = bv;
    __syncthreads();
    if (k0 + BK < K) {
      Af += BK; Ah += BK; Bp += BK;
      if (AF32) {
        float4 f0 = *(const float4*)Af;
        float4 f1 = *(const float4*)(Af + 4);
        av.x = pack_bf2(f0.x, f0.y); av.y = pack_bf2(f0.z, f0.w);
        av.z = pack_bf2(f1.x, f1.y); av.w = pack_bf2(f1.z, f1.w);
      } else {
        av = *(const uint4*)Ah;
      }
      bv = *(const uint4*)Bp;
    }
    bf16x8 a0 = *(const bf16x8*)&As[(wr +      l15) * KP + k8];
    bf16x8 a1 = *(const bf16x8*)&As[(wr + 16 + l15) * KP + k8];
    bf16x8 b0 = *(const bf16x8*)&Bs[(wc +      l15) * KP + k8];
    bf16x8 b1 = *(const bf16x8*)&Bs[(wc + 16 + l15) * KP + k8];
    acc00 = __builtin_amdgcn_mfma_f32_16x16x32_bf16(a0, b0, acc00, 0, 0, 0);
    acc01 = __builtin_amdgcn_mfma_f32_16x16x32_bf16(a0, b1, acc01, 0, 0, 0);
    acc10 = __builtin_amdgcn_mfma_f32_16x16x32_bf16(a1, b0, acc10, 0, 0, 0);
    acc11 = __builtin_amdgcn_mfma_f32_16x16x32_bf16(a1, b1, acc11, 0, 0, 0);
  }

  int rbase = (lane >> 4) * 4;
#pragma unroll
  for (int r = 0; r < 4; ++r) {
    size_t row0 = (size_t)(bm + wr +      rbase + r) * N + bn + wc;
    size_t row1 = (size_t)(bm + wr + 16 + rbase + r) * N + bn + wc;
    if (CF32) {
      float* C = (float*)Cv;
      C[row0 +      l15] = acc00[r];
      C[row0 + 16 + l15] = acc01[r];
      C[row1 +      l15] = acc10[r];
      C[row1 + 16 + l15] = acc11[r];
    } else {
      ushort* C = (ushort*)Cv;
      C[row0 +      l15] = f2bf(acc00[r]);
      C[row0 + 16 + l15] = f2bf(acc01[r]);
      C[row1 +      l15] = f2bf(acc10[r]);
      C[row1 + 16 + l15] = f2bf(acc11[r]);
    }
  }
}

#define GKP 40
template<bool AF32, bool CF32>
__global__ __launch_bounds__(256) void gemm128(
    const void* __restrict__ Av, const ushort* __restrict__ Bt,
    void* __restrict__ Cv, int M, int N, int K)
{
  __shared__ ushort As[128 * GKP];
  __shared__ ushort Bs[128 * GKP];
  int tid  = threadIdx.x;
  int bm   = blockIdx.y * 128;
  int bn   = blockIdx.x * 128;
  int wave = tid >> 6;
  int lane = tid & 63;
  int wr   = (wave >> 1) * 64;
  int wc   = (wave & 1) * 64;
  int l15  = lane & 15;
  int quad = lane >> 4;
  int k8   = quad * 8;

  int srow = tid >> 1;
  int scol = (tid & 1) * 16;

  const float*  Af = (const float*)Av  + (size_t)(bm + srow) * K + scol;
  const ushort* Ah = (const ushort*)Av + (size_t)(bm + srow) * K + scol;
  const ushort* Bp = Bt + (size_t)(bn + srow) * K + scol;

  floatx4 acc[4][4];
#pragma unroll
  for (int i = 0; i < 4; ++i)
#pragma unroll
    for (int j = 0; j < 4; ++j) acc[i][j] = floatx4{0,0,0,0};

  uint4 av0, av1, bv0, bv1;
  if (AF32) {
    float4 f0 = *(const float4*)Af,      f1 = *(const float4*)(Af + 4);
    float4 f2 = *(const float4*)(Af + 8), f3 = *(const float4*)(Af + 12);
    av0.x = pack_bf2(f0.x, f0.y); av0.y = pack_bf2(f0.z, f0.w);
    av0.z = pack_bf2(f1.x, f1.y); av0.w = pack_bf2(f1.z, f1.w);
    av1.x = pack_bf2(f2.x, f2.y); av1.y = pack_bf2(f2.z, f2.w);
    av1.z = pack_bf2(f3.x, f3.y); av1.w = pack_bf2(f3.z, f3.w);
  } else {
    av0 = *(const uint4*)Ah; av1 = *(const uint4*)(Ah + 8);
  }
  bv0 = *(const uint4*)Bp; bv1 = *(const uint4*)(Bp + 8);

  for (int k0 = 0; k0 < K; k0 += 32) {
    __syncthreads();
    *(uint4*)&As[srow * GKP + scol]     = av0;
    *(uint4*)&As[srow * GKP + scol + 8] = av1;
    *(uint4*)&Bs[srow * GKP + scol]     = bv0;
    *(uint4*)&Bs[srow * GKP + scol + 8] = bv1;
    __syncthreads();
    if (k0 + 32 < K) {
      Af += 32; Ah += 32; Bp += 32;
      if (AF32) {
        float4 f0 = *(const float4*)Af,      f1 = *(const float4*)(Af + 4);
        float4 f2 = *(const float4*)(Af + 8), f3 = *(const float4*)(Af + 12);
        av0.x = pack_bf2(f0.x, f0.y); av0.y = pack_bf2(f0.z, f0.w);
        av0.z = pack_bf2(f1.x, f1.y); av0.w = pack_bf2(f1.z, f1.w);
        av1.x = pack_bf2(f2.x, f2.y); av1.y = pack_bf2(f2.z, f2.w);
        av1.z = pack_bf2(f3.x, f3.y); av1.w = pack_bf2(f3.z, f3.w);
      } else {
        av0 = *(const uint4*)Ah; av1 = *(const uint4*)(Ah + 8);
      }
      bv0 = *(const uint4*)Bp; bv1 = *(const uint4*)(Bp + 8);
    }
    bf16x8 a[4], b[4];
#pragma unroll
    for (int t = 0; t < 4; ++t) {
      a[t] = *(const bf16x8*)&As[(wr + t * 16 + l15) * GKP + k8];
      b[t] = *(const bf16x8*)&Bs[(wc + t * 16 + l15) * GKP + k8];
    }
#pragma unroll
    for (int mt = 0; mt < 4; ++mt)
#pragma unroll
      for (int nt = 0; nt < 4; ++nt)
        acc[mt][nt] = __builtin_amdgcn_mfma_f32_16x16x32_bf16(a[mt], b[nt], acc[mt][nt], 0, 0, 0);
  }

#pragma unroll
  for (int mt = 0; mt < 4; ++mt)
#pragma unroll
    for (int nt = 0; nt < 4; ++nt)
#pragma unroll
      for (int r = 0; r < 4; ++r) {
        size_t idx = (size_t)(bm + wr + mt * 16 + quad * 4 + r) * N
                     + bn + wc + nt * 16 + l15;
        if (CF32) ((float*)Cv)[idx] = acc[mt][nt][r];
        else      ((ushort*)Cv)[idx] = f2bf(acc[mt][nt][r]);
      }
}

// ------- flash attention, legacy (fallback path) ----------------------------
#define QP 72
#define PP 72

__global__ __launch_bounds__(256) void gqa_attn(
    const ushort* __restrict__ q_buf,  // [B*S, DIM]
    const ushort* __restrict__ k_buf,  // [B*S, 512]
    const ushort* __restrict__ vT,     // [B, 512, S]
    ushort* __restrict__ attn)         // [B*S, DIM]
{
  __shared__ __align__(16) ushort Qs[64 * QP];
  __shared__ __align__(16) ushort Ks[64 * QP];
  __shared__ __align__(16) ushort Vs[64 * QP];
  __shared__ __align__(16) ushort Ps[4][16 * PP];  // wave-private

  int bid = blockIdx.x;
  int qt  = bid & 31;
  int g   = (bid >> 5) & 3;
  int h   = (bid >> 7) & 7;
  int b   = bid >> 10;

  int tid  = threadIdx.x;
  int wave = tid >> 6;
  int lane = tid & 63;
  int l15  = lane & 15;
  int quad = lane >> 4;
  int k8   = quad * 8;

  int srow = tid >> 2;
  int c16  = (tid & 3) * 16;

  {
    const ushort* src = q_buf + (size_t)(b * SEQ + qt * 64 + srow) * DIM
                        + (h * NGRP + g) * HDIM + c16;
    *(uint4*)&Qs[srow * QP + c16]     = *(const uint4*)src;
    *(uint4*)&Qs[srow * QP + c16 + 8] = *(const uint4*)(src + 8);
  }
  __syncthreads();

  bf16x8 bq0 = *(const bf16x8*)&Qs[(wave * 16 + l15) * QP + k8];
  bf16x8 bq1 = *(const bf16x8*)&Qs[(wave * 16 + l15) * QP + 32 + k8];

  float lpart = 0.f;
  floatx4 oarr[4] = {{0,0,0,0},{0,0,0,0},{0,0,0,0},{0,0,0,0}};

  const ushort* kp = k_buf + (size_t)(b * SEQ + srow) * KVDIM + h * HDIM + c16;
  const ushort* vp = vT + ((size_t)(b * NKV + h) * HDIM + srow) * SEQ + c16;

  uint4 kv0 = *(const uint4*)kp;
  uint4 kv1 = *(const uint4*)(kp + 8);
  uint4 vv0 = *(const uint4*)vp;
  uint4 vv1 = *(const uint4*)(vp + 8);

  ushort* Pw = &Ps[wave][0];

  for (int kt = 0; kt < SEQ / 64; ++kt) {
    __syncthreads();
    *(uint4*)&Ks[srow * QP + c16]     = kv0;
    *(uint4*)&Ks[srow * QP + c16 + 8] = kv1;
    *(uint4*)&Vs[srow * QP + c16]     = vv0;
    *(uint4*)&Vs[srow * QP + c16 + 8] = vv1;
    __syncthreads();
    if (kt + 1 < SEQ / 64) {
      kp += (size_t)64 * KVDIM;
      vp += 64;
      kv0 = *(const uint4*)kp;
      kv1 = *(const uint4*)(kp + 8);
      vv0 = *(const uint4*)vp;
      vv1 = *(const uint4*)(vp + 8);
    }

    floatx4 sarr[4];
#pragma unroll
    for (int nt = 0; nt < 4; ++nt) {
      bf16x8 ak0 = *(const bf16x8*)&Ks[(nt * 16 + l15) * QP + k8];
      bf16x8 ak1 = *(const bf16x8*)&Ks[(nt * 16 + l15) * QP + 32 + k8];
      floatx4 s = {0.f, 0.f, 0.f, 0.f};
      s = __builtin_amdgcn_mfma_f32_16x16x32_bf16(ak0, bq0, s, 0, 0, 0);
      s = __builtin_amdgcn_mfma_f32_16x16x32_bf16(ak1, bq1, s, 0, 0, 0);
      sarr[nt] = s;
    }

#pragma unroll
    for (int nt = 0; nt < 4; ++nt) {
      float p0 = __expf(sarr[nt][0] * 0.125f);
      float p1 = __expf(sarr[nt][1] * 0.125f);
      float p2 = __expf(sarr[nt][2] * 0.125f);
      float p3 = __expf(sarr[nt][3] * 0.125f);
      lpart += (p0 + p1) + (p2 + p3);
      uint2 pw;
      pw.x = pack_bf2(p0, p1);
      pw.y = pack_bf2(p2, p3);
      *(uint2*)&Pw[l15 * PP + nt * 16 + quad * 4] = pw;
    }

    bf16x8 ap0 = *(const bf16x8*)&Pw[l15 * PP + k8];
    bf16x8 ap1 = *(const bf16x8*)&Pw[l15 * PP + 32 + k8];
#pragma unroll
    for (int dt = 0; dt < 4; ++dt) {
      bf16x8 bv0q = *(const bf16x8*)&Vs[(dt * 16 + l15) * QP + k8];
      bf16x8 bv1q = *(const bf16x8*)&Vs[(dt * 16 + l15) * QP + 32 + k8];
      oarr[dt] = __builtin_amdgcn_mfma_f32_16x16x32_bf16(ap0, bv0q, oarr[dt], 0, 0, 0);
      oarr[dt] = __builtin_amdgcn_mfma_f32_16x16x32_bf16(ap1, bv1q, oarr[dt], 0, 0, 0);
    }
  }

  float ls = lpart;
  ls += __shfl_xor(ls, 16, 64);
  ls += __shfl_xor(ls, 32, 64);

  __syncthreads();
  float* Lw = (float*)Pw;
  if (quad == 0) Lw[l15] = ls;
  __syncthreads();

#pragma unroll
  for (int r = 0; r < 4; ++r) {
    float inv = 1.0f / Lw[quad * 4 + r];
    int q = qt * 64 + wave * 16 + quad * 4 + r;
    size_t rowoff = (size_t)(b * SEQ + q) * DIM + (h * NGRP + g) * HDIM;
#pragma unroll
    for (int dt = 0; dt < 4; ++dt)
      attn[rowoff + dt * 16 + l15] = f2bf(oarr[dt][r] * inv);
  }
}

// ------- flash attention v3c: g-fused, VALU-lean softmax (FROZEN, round 6) --
__global__ __launch_bounds__(256, 2) void gqa_attn3(
    const ushort* __restrict__ qkv,  // [B*S, 3072] : q[0,2048) k[2048,2560) v[2560,3072)
    const ushort* __restrict__ vT,   // [B, 512, S]
    ushort* __restrict__ attn)       // [B*S, DIM]
{
  __shared__ __align__(16) ushort Ks[64 * QP];     // 9216 B
  __shared__ __align__(16) ushort Vs[64 * QP];     // 9216 B
  __shared__ __align__(16) ushort Ps[4][16 * PP];  // 9216 B, wave-private

  int bid = blockIdx.x;
  int qt  = bid & 31;          // 32 q-tiles of 64 rows
  int h   = (bid >> 5) & 7;
  int b   = bid >> 8;

  int tid  = threadIdx.x;
  int wave = tid >> 6;
  int lane = tid & 63;
  int l15  = lane & 15;
  int quad = lane >> 4;
  int k8   = quad * 8;

  int srow = tid >> 2;
  int c16  = (tid & 3) * 16;

  // Q fragments for all 4 g's, loaded once and pre-scaled by 0.125 (exact)
  bf16x8 bq[NGRP][2];
  {
    const ushort* qrow = qkv + (size_t)(b * SEQ + qt * 64 + wave * 16 + l15) * QKVD
                         + h * NGRP * HDIM;
#pragma unroll
    for (int g = 0; g < NGRP; ++g) {
      bq[g][0] = *(const bf16x8*)(qrow + g * HDIM + k8);
      bq[g][1] = *(const bf16x8*)(qrow + g * HDIM + 32 + k8);
    }
  }
#pragma unroll
  for (int g = 0; g < NGRP; ++g)
#pragma unroll
    for (int j = 0; j < 2; ++j)
#pragma unroll
      for (int e = 0; e < 8; ++e)
        bq[g][j][e] = (__bf16)((float)bq[g][j][e] * 0.125f);

  bf16x8 vones;
#pragma unroll
  for (int i = 0; i < 8; ++i) vones[i] = (__bf16)1.0f;

  floatx4 lacc[NGRP];
  floatx4 oacc[NGRP][4];
#pragma unroll
  for (int g = 0; g < NGRP; ++g) {
    lacc[g] = floatx4{0,0,0,0};
#pragma unroll
    for (int dt = 0; dt < 4; ++dt) oacc[g][dt] = floatx4{0,0,0,0};
  }

  const ushort* kp = qkv + (size_t)(b * SEQ + srow) * QKVD + DIM + h * HDIM + c16;
  const ushort* vp = vT + ((size_t)(b * NKV + h) * HDIM + srow) * SEQ + c16;

  uint4 kv0 = *(const uint4*)kp;
  uint4 kv1 = *(const uint4*)(kp + 8);
  uint4 vv0 = *(const uint4*)vp;
  uint4 vv1 = *(const uint4*)(vp + 8);

  ushort* Pw = &Ps[wave][0];

  for (int kt = 0; kt < SEQ / 64; ++kt) {
    __syncthreads();
    *(uint4*)&Ks[srow * QP + c16]     = kv0;
    *(uint4*)&Ks[srow * QP + c16 + 8] = kv1;
    *(uint4*)&Vs[srow * QP + c16]     = vv0;
    *(uint4*)&Vs[srow * QP + c16 + 8] = vv1;
    __syncthreads();
    if (kt + 1 < SEQ / 64) {
      kp += (size_t)64 * QKVD;
      vp += 64;
      kv0 = *(const uint4*)kp;
      kv1 = *(const uint4*)(kp + 8);
      vv0 = *(const uint4*)vp;
      vv1 = *(const uint4*)(vp + 8);
    }

    // hoist K/V fragments to registers ONCE per tile (shared by all g)
    bf16x8 ak[4][2], av[4][2];
#pragma unroll
    for (int t = 0; t < 4; ++t) {
      ak[t][0] = *(const bf16x8*)&Ks[(t * 16 + l15) * QP + k8];
      ak[t][1] = *(const bf16x8*)&Ks[(t * 16 + l15) * QP + 32 + k8];
      av[t][0] = *(const bf16x8*)&Vs[(t * 16 + l15) * QP + k8];
      av[t][1] = *(const bf16x8*)&Vs[(t * 16 + l15) * QP + 32 + k8];
    }

#pragma unroll
    for (int g = 0; g < NGRP; ++g) {
      // --- S^T = K . Q^T for group g : lane holds 16 keys for q = l15 ---
#pragma unroll
      for (int nt = 0; nt < 4; ++nt) {
        floatx4 s = {0.f, 0.f, 0.f, 0.f};
        s = __builtin_amdgcn_mfma_f32_16x16x32_bf16(ak[nt][0], bq[g][0], s, 0, 0, 0);
        s = __builtin_amdgcn_mfma_f32_16x16x32_bf16(ak[nt][1], bq[g][1], s, 0, 0, 0);
        float p0 = __expf(s[0]);
        float p1 = __expf(s[1]);
        float p2 = __expf(s[2]);
        float p3 = __expf(s[3]);
        uint2 pw;
        pw.x = pack_bf2_rn(p0, p1);
        pw.y = pack_bf2_rn(p2, p3);
        *(uint2*)&Pw[l15 * PP + nt * 16 + quad * 4] = pw;
      }

      // fence: order P writes (uint2) before P reads (bf16x8) — distinct TBAA
      // types, compiler must not reorder; DS is in-order per wave in HW.
      asm volatile("" ::: "memory");

      bf16x8 ap0 = *(const bf16x8*)&Pw[l15 * PP + k8];
      bf16x8 ap1 = *(const bf16x8*)&Pw[l15 * PP + 32 + k8];
      // l[q] = sum_k P[q][k] via MFMA against ones (all output cols equal)
      lacc[g] = __builtin_amdgcn_mfma_f32_16x16x32_bf16(ap0, vones, lacc[g], 0, 0, 0);
      lacc[g] = __builtin_amdgcn_mfma_f32_16x16x32_bf16(ap1, vones, lacc[g], 0, 0, 0);
#pragma unroll
      for (int dt = 0; dt < 4; ++dt) {
        oacc[g][dt] = __builtin_amdgcn_mfma_f32_16x16x32_bf16(ap0, av[dt][0], oacc[g][dt], 0, 0, 0);
        oacc[g][dt] = __builtin_amdgcn_mfma_f32_16x16x32_bf16(ap1, av[dt][1], oacc[g][dt], 0, 0, 0);
      }

      // fence: order this g's P reads before next g's P writes (WAR)
      asm volatile("" ::: "memory");
    }
  }

  // epilogue: lacc[g][r] = l[q = quad*4+r] in every lane — no cross-lane comm
#pragma unroll
  for (int g = 0; g < NGRP; ++g) {
#pragma unroll
    for (int r = 0; r < 4; ++r) {
      float inv = 1.0f / lacc[g][r];
      int q = qt * 64 + wave * 16 + quad * 4 + r;
      size_t rowoff = (size_t)(b * SEQ + q) * DIM + (h * NGRP + g) * HDIM;
#pragma unroll
      for (int dt = 0; dt < 4; ++dt)
        attn[rowoff + dt * 16 + l15] = f2bf(oacc[g][dt][r] * inv);
    }
  }
}

// ---------------- launch ----------------------------------------------------
extern "C" void kernel_launch(void* const* d_in, const int* in_sizes, int n_in,
                              void* d_out, int out_size, void* d_ws, size_t ws_size,
                              hipStream_t stream)
{
  (void)in_sizes; (void)n_in; (void)out_size;
  const float* x  = (const float*)d_in[0];
  const float* Wq = (const float*)d_in[1];
  const float* Wk = (const float*)d_in[2];
  const float* Wv = (const float*)d_in[3];
  const float* Wo = (const float*)d_in[4];
  float*  outf = (float*)d_out;
  ushort* ob   = (ushort*)d_out;
  ushort* ws16 = (ushort*)d_ws;

  const size_t Mi = 1024 * 1024;
  dim3 blk(256);
  const int M = BATCH * SEQ;

  if (ws_size >= 40u * Mi) {
    // ---- new path: fused QKV projection + g-fused attention ----
    // ws (Mi ushorts): WqkvT[0,6) = WqT|WkT|WvT as [3072,2048]; WoT[8,12);
    //                  xb[12,20) -> ao[12,20) after projection
    // d_out scratch:   qkv[0,12) = [4096,3072]; vt[12,14)
    ushort* WqkvT = ws16;
    ushort* WoT   = ws16 + 8 * Mi;
    ushort* xb    = ws16 + 12 * Mi;
    ushort* ao    = ws16 + 12 * Mi;   // overlays xb (dead after projection)
    ushort* qkv   = ob;
    ushort* vt    = ob + 12 * Mi;

    // one prep launch: x->bf16 (blocks 0..4095) + all weight transposes
    prep_all<<<dim3(4096 + 2560), blk, 0, stream>>>(x, Wq, Wk, Wv, Wo, xb, WqkvT, WoT);

    // one GEMM for q|k|v : [4096,2048] @ [2048,3072] -> [4096,3072]
    gemm_lds<false><<<dim3(QKVD / 128, M / 128), blk, 0, stream>>>(xb, WqkvT, qkv, M, QKVD, DIM);

    // V^T for the PV step: slice cols [2560,3072) of qkv, per batch
    transpose_b2b<<<dim3(KVDIM / 64, SEQ / 64, BATCH), blk, 0, stream>>>(
        qkv + 2560, vt, SEQ, KVDIM, QKVD, (size_t)SEQ * QKVD, (size_t)KVDIM * SEQ);

    gqa_attn3<<<dim3(BATCH * NKV * (SEQ / 64)), blk, 0, stream>>>(qkv, vt, ao);

    gemm_lds<true><<<dim3(DIM / 128, M / 128), blk, 0, stream>>>(ao, WoT, outf, M, DIM, DIM);
  } else {
    // ---- fallback: round-4 structure (proven, ws <= 24 MiB) ----
    ushort* qb  = ob;
    ushort* kb  = ob + 8 * Mi;
    ushort* vb  = ob + 10 * Mi;
    ushort* vt  = ob + 12 * Mi;
    ushort* WqT = ws16;
    ushort* WkT = ws16 + 4 * Mi;
    ushort* WvT = ws16 + 5 * Mi;
    ushort* WoT = ws16 + 8 * Mi;
    ushort* ao  = ws16;

    transpose_f2b<<<dim3(DIM / 64,   DIM / 64), blk, 0, stream>>>(Wq, WqT, DIM, DIM);
    transpose_f2b<<<dim3(KVDIM / 64, DIM / 64), blk, 0, stream>>>(Wk, WkT, DIM, KVDIM);
    transpose_f2b<<<dim3(KVDIM / 64, DIM / 64), blk, 0, stream>>>(Wv, WvT, DIM, KVDIM);
    transpose_f2b<<<dim3(DIM / 64,   DIM / 64), blk, 0, stream>>>(Wo, WoT, DIM, DIM);

    gemm128<true, false><<<dim3(DIM / 128, M / 128), blk, 0, stream>>>(x, WqT, qb, M, DIM, DIM);
    gemm_abt<true, false><<<dim3(KVDIM / BN, M / BM), blk, 0, stream>>>(x, WkT, kb, M, KVDIM, DIM);
    gemm_abt<true, false><<<dim3(KVDIM / BN, M / BM), blk, 0, stream>>>(x, WvT, vb, M, KVDIM, DIM);

    transpose_b2b<<<dim3(KVDIM / 64, SEQ / 64, BATCH), blk, 0, stream>>>(
        vb, vt, SEQ, KVDIM, KVDIM, (size_t)SEQ * KVDIM, (size_t)KVDIM * SEQ);

    gqa_attn<<<dim3(BATCH * NKV * NGRP * (SEQ / 64)), blk, 0, stream>>>(qb, kb, vt, ao);

    gemm128<false, true><<<dim3(DIM / 128, M / 128), blk, 0, stream>>>(ao, WoT, outf, M, DIM, DIM);
  }
}

// Round 10
// 309.711 us; speedup vs baseline: 1.0622x; 1.0622x over previous
//
#include <hip/hip_runtime.h>
#include <hip/hip_bf16.h>

typedef __bf16 bf16x8 __attribute__((ext_vector_type(8)));
typedef float floatx4 __attribute__((ext_vector_type(4)));

#define DIM   2048
#define SEQ   2048
#define BATCH 2
#define NKV   8
#define NGRP  4
#define HDIM  64
#define KVDIM (NKV * HDIM)   // 512
#define QKVD  3072           // fused q|k|v projection width

__device__ __forceinline__ ushort f2bf(float f) {          // RNE
  union { float f; unsigned u; } x; x.f = f;
  return (ushort)((x.u + 0x7fffu + ((x.u >> 16) & 1u)) >> 16);
}
// pack two floats -> two bf16 in one u32 (round-half-up, bit trick)
__device__ __forceinline__ unsigned pack_bf2(float a, float b) {
  union { float f; unsigned u; } x, y; x.f = a; y.f = b;
  unsigned ua = x.u + 0x8000u, ub = y.u + 0x8000u;
  return __builtin_amdgcn_perm(ub, ua, 0x07060302);
}
// pack two floats -> two bf16 (RNE, matches f2bf-ish) via bit ops
__device__ __forceinline__ unsigned pack_bf2_rne(float a, float b) {
  return (unsigned)f2bf(a) | ((unsigned)f2bf(b) << 16);
}
// pack two floats -> two bf16 in one u32 via v_cvt_pk_bf16_f32 (RNE, 1 instr)
__device__ __forceinline__ unsigned pack_bf2_rn(float a, float b) {
  __hip_bfloat162 h = __float22bfloat162_rn(make_float2(a, b));
  union { __hip_bfloat162 h; unsigned u; } cv; cv.h = h; return cv.u;
}

typedef const __attribute__((address_space(1))) void* gas_t;
typedef __attribute__((address_space(3))) void* las_t;
__device__ __forceinline__ void gload_lds16(const ushort* g, ushort* l) {
  __builtin_amdgcn_global_load_lds((gas_t)g, (las_t)l, 16, 0, 0);
}

// ------- x fp32 -> bf16 bulk convert (fallback body) -------------------------
__global__ __launch_bounds__(256) void cvt_f2b(
    const float* __restrict__ in, ushort* __restrict__ out)
{
  int i = blockIdx.x * 256 + threadIdx.x;     // one uint4 (8 bf16) per thread
  const float4* p = (const float4*)in + (size_t)i * 2;
  float4 f0 = p[0], f1 = p[1];
  uint4 v;
  v.x = pack_bf2(f0.x, f0.y); v.y = pack_bf2(f0.z, f0.w);
  v.z = pack_bf2(f1.x, f1.y); v.w = pack_bf2(f1.z, f1.w);
  ((uint4*)out)[i] = v;
}

// ------- transpose + convert: fp32 [R,C] -> bf16 [C,R] (weights) ------------
__global__ __launch_bounds__(256) void transpose_f2b(
    const float* __restrict__ in, ushort* __restrict__ out, int R, int C)
{
  __shared__ ushort tileT[64][72];
  int tr = blockIdx.y * 64;
  int tc = blockIdx.x * 64;
  int row = threadIdx.x >> 2;
  int c16 = (threadIdx.x & 3) * 16;

  ushort arr[16];
  const float* src = in + (size_t)(tr + row) * C + tc + c16;
#pragma unroll
  for (int q = 0; q < 4; ++q) {
    float4 f = *(const float4*)(src + q * 4);
    arr[q * 4 + 0] = f2bf(f.x); arr[q * 4 + 1] = f2bf(f.y);
    arr[q * 4 + 2] = f2bf(f.z); arr[q * 4 + 3] = f2bf(f.w);
  }
  int rot = row & 15;
#pragma unroll
  for (int j = 0; j < 16; ++j) {
    int i2 = (j + rot) & 15;
    tileT[c16 + i2][row] = arr[i2];
  }
  __syncthreads();
  ushort* dst = out + (size_t)(tc + row) * R + tr + c16;
  *(uint4*)dst       = *(const uint4*)&tileT[row][c16];
  *(uint4*)(dst + 8) = *(const uint4*)&tileT[row][c16 + 8];
}

// ------- fused prep: x convert (blocks 0..4095) + 4 weight transposes -------
__global__ __launch_bounds__(256) void prep_all(
    const float* __restrict__ x,
    const float* __restrict__ Wq, const float* __restrict__ Wk,
    const float* __restrict__ Wv, const float* __restrict__ Wo,
    ushort* __restrict__ xb, ushort* __restrict__ WqkvT, ushort* __restrict__ WoT)
{
  __shared__ ushort tileT[64][72];
  int bid = blockIdx.x;
  if (bid < 4096) {                 // ---- cvt: x fp32 -> bf16 ----
    int i = bid * 256 + threadIdx.x;
    const float4* p = (const float4*)x + (size_t)i * 2;
    float4 f0 = p[0], f1 = p[1];
    uint4 v;
    v.x = pack_bf2(f0.x, f0.y); v.y = pack_bf2(f0.z, f0.w);
    v.z = pack_bf2(f1.x, f1.y); v.w = pack_bf2(f1.z, f1.w);
    ((uint4*)xb)[i] = v;
    return;
  }
  // ---- weight transposes ----
  const size_t Mi = 1024 * 1024;
  int id = bid - 4096;
  const float* in; ushort* out; int C;
  if (id < 1024)      { in = Wq; out = WqkvT;          C = 2048; }
  else if (id < 1280) { in = Wk; out = WqkvT + 4 * Mi; C = 512;  id -= 1024; }
  else if (id < 1536) { in = Wv; out = WqkvT + 5 * Mi; C = 512;  id -= 1280; }
  else                { in = Wo; out = WoT;            C = 2048; id -= 1536; }
  const int R = 2048;
  int nbx = C / 64;
  int tr = (id / nbx) * 64;
  int tc = (id % nbx) * 64;
  int row = threadIdx.x >> 2;
  int c16 = (threadIdx.x & 3) * 16;

  ushort arr[16];
  const float* src = in + (size_t)(tr + row) * C + tc + c16;
#pragma unroll
  for (int q = 0; q < 4; ++q) {
    float4 f = *(const float4*)(src + q * 4);
    arr[q * 4 + 0] = f2bf(f.x); arr[q * 4 + 1] = f2bf(f.y);
    arr[q * 4 + 2] = f2bf(f.z); arr[q * 4 + 3] = f2bf(f.w);
  }
  int rot = row & 15;
#pragma unroll
  for (int j = 0; j < 16; ++j) {
    int i2 = (j + rot) & 15;
    tileT[c16 + i2][row] = arr[i2];
  }
  __syncthreads();
  ushort* dst = out + (size_t)(tc + row) * R + tr + c16;
  *(uint4*)dst       = *(const uint4*)&tileT[row][c16];
  *(uint4*)(dst + 8) = *(const uint4*)&tileT[row][c16 + 8];
}

// ------- transpose bf16 [R,C] (strided rows) -> bf16 [C,R], batched ---------
// (fallback path only; main path fuses V^T into the QKV GEMM epilogue)
__global__ __launch_bounds__(256) void transpose_b2b(
    const ushort* __restrict__ in, ushort* __restrict__ out,
    int R, int C, int in_stride, size_t in_batch, size_t out_batch)
{
  __shared__ ushort tileT[64][72];
  in  += (size_t)blockIdx.z * in_batch;
  out += (size_t)blockIdx.z * out_batch;
  int tr = blockIdx.y * 64;
  int tc = blockIdx.x * 64;
  int row = threadIdx.x >> 2;
  int c16 = (threadIdx.x & 3) * 16;

  ushort arr[16];
  const ushort* src = in + (size_t)(tr + row) * in_stride + tc + c16;
  *(uint4*)&arr[0] = *(const uint4*)src;
  *(uint4*)&arr[8] = *(const uint4*)(src + 8);
  int rot = row & 15;
#pragma unroll
  for (int j = 0; j < 16; ++j) {
    int i2 = (j + rot) & 15;
    tileT[c16 + i2][row] = arr[i2];
  }
  __syncthreads();
  ushort* dst = out + (size_t)(tc + row) * R + tr + c16;
  *(uint4*)dst       = *(const uint4*)&tileT[row][c16];
  *(uint4*)(dst + 8) = *(const uint4*)&tileT[row][c16 + 8];
}

// ------- 2-phase m97 GEMM (round-8 proven): C = A @ Bt^T, bf16 --------------
// 128x128 tile, BK=32 double-buffered (32 KB LDS). barrier -> issue
// STAGE(buf^1, t+1) -> compute buf[cur]. One barrier per K-step.
// XCD-aware block swizzle (bijective when nwg%8==0).
// vtOut != nullptr (QKV call): V-region blocks (bn >= 2560) additionally
// write V^T into vt[(b*512+c)*SEQ + seq] from the accumulators — each lane's
// acc[mt][nt][0..3] is 4 consecutive seq rows of one vt column (two aligned
// 4B stores). Values bit-identical to transposing the rounded C output.
template<bool CF32>
__global__ __launch_bounds__(256) void gemm_lds(
    const ushort* __restrict__ A, const ushort* __restrict__ Bt,
    void* __restrict__ Cv, ushort* __restrict__ vtOut, int M, int N, int K)
{
  __shared__ ushort As[2][128 * 32];   // 8 KB each
  __shared__ ushort Bs[2][128 * 32];
  int tid  = threadIdx.x;

  int gx  = gridDim.x;
  int nwg = gx * gridDim.y;
  int lin = blockIdx.y * gx + blockIdx.x;
  if ((nwg & 7) == 0) {                 // XCD swizzle, bijective
    int cpx = nwg >> 3;
    lin = (lin & 7) * cpx + (lin >> 3);
  }
  int bm = (lin / gx) * 128;
  int bn = (lin % gx) * 128;

  int wv   = tid >> 6;
  int ln   = tid & 63;
  int wr   = (wv >> 1) * 64;
  int wc   = (wv & 1) * 64;
  int l15  = ln & 15;
  int quad = ln >> 4;

  // staging: wave wv fills rows 32wv..32wv+31; issue i covers rows +16i.
  // lane: row = 32wv+16i+(ln>>2), col = (ln&3)*8 ; LDS chunk = base + ln*16B
  int r4 = ln >> 2;
  int c8 = (ln & 3) * 8;
  const ushort* Ag0 = A  + (size_t)(bm + 32 * wv +      r4) * K + c8;
  const ushort* Ag1 = A  + (size_t)(bm + 32 * wv + 16 + r4) * K + c8;
  const ushort* Bg0 = Bt + (size_t)(bn + 32 * wv +      r4) * K + c8;
  const ushort* Bg1 = Bt + (size_t)(bn + 32 * wv + 16 + r4) * K + c8;
  int st0 = 1024 * wv +       ln * 8;
  int st1 = 1024 * wv + 512 + ln * 8;

  floatx4 acc[4][4];
#pragma unroll
  for (int i = 0; i < 4; ++i)
#pragma unroll
    for (int j = 0; j < 4; ++j) acc[i][j] = floatx4{0,0,0,0};

  // prologue: stage K-step 0 into buf 0
  gload_lds16(Ag0, &As[0][0] + st0);
  gload_lds16(Ag1, &As[0][0] + st1);
  gload_lds16(Bg0, &Bs[0][0] + st0);
  gload_lds16(Bg1, &Bs[0][0] + st1);
  Ag0 += 32; Ag1 += 32; Bg0 += 32; Bg1 += 32;

  int cur = 0;
  for (int k0 = 0; k0 < K; k0 += 32) {
    __syncthreads();        // drains vmcnt(0): buf[cur] ready; joins all waves'
                            // completed reads of buf[cur^1]
    if (k0 + 32 < K) {      // issue next-tile stage BEFORE compute (overlap)
      ushort* Ad = &As[cur ^ 1][0];
      ushort* Bd = &Bs[cur ^ 1][0];
      gload_lds16(Ag0, Ad + st0);
      gload_lds16(Ag1, Ad + st1);
      gload_lds16(Bg0, Bd + st0);
      gload_lds16(Bg1, Bd + st1);
      Ag0 += 32; Ag1 += 32; Bg0 += 32; Bg1 += 32;
    }

    bf16x8 a[4], b[4];
#pragma unroll
    for (int t = 0; t < 4; ++t) {
      a[t] = *(const bf16x8*)&As[cur][(wr + t * 16 + l15) * 32 + quad * 8];
      b[t] = *(const bf16x8*)&Bs[cur][(wc + t * 16 + l15) * 32 + quad * 8];
    }
#pragma unroll
    for (int mt = 0; mt < 4; ++mt)
#pragma unroll
      for (int nt = 0; nt < 4; ++nt)
        acc[mt][nt] = __builtin_amdgcn_mfma_f32_16x16x32_bf16(a[mt], b[nt], acc[mt][nt], 0, 0, 0);
    cur ^= 1;
  }

#pragma unroll
  for (int mt = 0; mt < 4; ++mt)
#pragma unroll
    for (int nt = 0; nt < 4; ++nt)
#pragma unroll
      for (int r = 0; r < 4; ++r) {
        size_t idx = (size_t)(bm + wr + mt * 16 + quad * 4 + r) * N
                     + bn + wc + nt * 16 + l15;
        if (CF32) ((float*)Cv)[idx] = acc[mt][nt][r];
        else      ((ushort*)Cv)[idx] = f2bf(acc[mt][nt][r]);
      }

  // fused V^T output (QKV call only; V-region blocks are bn>=2560 exactly)
  if (!CF32 && vtOut != nullptr && bn >= 2560) {
    int bb   = bm >> 11;               // batch (128-row tiles never straddle)
    int base = (bm & 2047) + wr;       // seq base of this wave
#pragma unroll
    for (int mt = 0; mt < 4; ++mt)
#pragma unroll
      for (int nt = 0; nt < 4; ++nt) {
        int c   = bn + wc + nt * 16 + l15 - 2560;       // vt column (0..511)
        int seq = base + mt * 16 + quad * 4;            // 4 consecutive rows
        ushort* vp = vtOut + ((size_t)bb * KVDIM + c) * SEQ + seq;
        *(unsigned*)(vp)     = pack_bf2_rne(acc[mt][nt][0], acc[mt][nt][1]);
        *(unsigned*)(vp + 2) = pack_bf2_rne(acc[mt][nt][2], acc[mt][nt][3]);
      }
  }
}

// ------- legacy GEMMs (fallback path) ---------------------------------------
#define BM 64
#define BN 64
#define BK 32
#define KP 40

template<bool AF32, bool CF32>
__global__ __launch_bounds__(256) void gemm_abt(
    const void* __restrict__ Av, const ushort* __restrict__ Bt,
    void* __restrict__ Cv, int M, int N, int K)
{
  __shared__ ushort As[BM * KP];
  __shared__ ushort Bs[BN * KP];
  int tid  = threadIdx.x;
  int bm   = blockIdx.y * BM;
  int bn   = blockIdx.x * BN;
  int wave = tid >> 6;
  int lane = tid & 63;
  int wr   = (wave >> 1) * 32;
  int wc   = (wave & 1) * 32;
  int l15  = lane & 15;
  int k8   = (lane >> 4) * 8;

  int srow = tid >> 2;
  int scol = (tid & 3) * 8;

  const float*  Af = (const float*)Av  + (size_t)(bm + srow) * K + scol;
  const ushort* Ah = (const ushort*)Av + (size_t)(bm + srow) * K + scol;
  const ushort* Bp = Bt + (size_t)(bn + srow) * K + scol;

  floatx4 acc00 = {0,0,0,0}, acc01 = {0,0,0,0}, acc10 = {0,0,0,0}, acc11 = {0,0,0,0};

  uint4 av, bv;
  if (AF32) {
    float4 f0 = *(const float4*)Af;
    float4 f1 = *(const float4*)(Af + 4);
    av.x = pack_bf2(f0.x, f0.y); av.y = pack_bf2(f0.z, f0.w);
    av.z = pack_bf2(f1.x, f1.y); av.w = pack_bf2(f1.z, f1.w);
  } else {
    av = *(const uint4*)Ah;
  }
  bv = *(const uint4*)Bp;

  for (int k0 = 0; k0 < K; k0 += BK) {
    __syncthreads();
    *(uint4*)&As[srow * KP + scol] = av;
    *(uint4*)&Bs[srow * KP + scol] = bv;
    __syncthreads();
    if (k0 + BK < K) {
      Af += BK; Ah += BK; Bp += BK;
      if (AF32) {
        float4 f0 = *(const float4*)Af;
        float4 f1 = *(const float4*)(Af + 4);
        av.x = pack_bf2(f0.x, f0.y); av.y = pack_bf2(f0.z, f0.w);
        av.z = pack_bf2(f1.x, f1.y); av.w = pack_bf2(f1.z, f1.w);
      } else {
        av = *(const uint4*)Ah;
      }
      bv = *(const uint4*)Bp;
    }
    bf16x8 a0 = *(const bf16x8*)&As[(wr +      l15) * KP + k8];
    bf16x8 a1 = *(const bf16x8*)&As[(wr + 16 + l15) * KP + k8];
    bf16x8 b0 = *(const bf16x8*)&Bs[(wc +      l15) * KP + k8];
    bf16x8 b1 = *(const bf16x8*)&Bs[(wc + 16 + l15) * KP + k8];
    acc00 = __builtin_amdgcn_mfma_f32_16x16x32_bf16(a0, b0, acc00, 0, 0, 0);
    acc01 = __builtin_amdgcn_mfma_f32_16x16x32_bf16(a0, b1, acc01, 0, 0, 0);
    acc10 = __builtin_amdgcn_mfma_f32_16x16x32_bf16(a1, b0, acc10, 0, 0, 0);
    acc11 = __builtin_amdgcn_mfma_f32_16x16x32_bf16(a1, b1, acc11, 0, 0, 0);
  }

  int rbase = (lane >> 4) * 4;
#pragma unroll
  for (int r = 0; r < 4; ++r) {
    size_t row0 = (size_t)(bm + wr +      rbase + r) * N + bn + wc;
    size_t row1 = (size_t)(bm + wr + 16 + rbase + r) * N + bn + wc;
    if (CF32) {
      float* C = (float*)Cv;
      C[row0 +      l15] = acc00[r];
      C[row0 + 16 + l15] = acc01[r];
      C[row1 +      l15] = acc10[r];
      C[row1 + 16 + l15] = acc11[r];
    } else {
      ushort* C = (ushort*)Cv;
      C[row0 +      l15] = f2bf(acc00[r]);
      C[row0 + 16 + l15] = f2bf(acc01[r]);
      C[row1 +      l15] = f2bf(acc10[r]);
      C[row1 + 16 + l15] = f2bf(acc11[r]);
    }
  }
}

#define GKP 40
template<bool AF32, bool CF32>
__global__ __launch_bounds__(256) void gemm128(
    const void* __restrict__ Av, const ushort* __restrict__ Bt,
    void* __restrict__ Cv, int M, int N, int K)
{
  __shared__ ushort As[128 * GKP];
  __shared__ ushort Bs[128 * GKP];
  int tid  = threadIdx.x;
  int bm   = blockIdx.y * 128;
  int bn   = blockIdx.x * 128;
  int wave = tid >> 6;
  int lane = tid & 63;
  int wr   = (wave >> 1) * 64;
  int wc   = (wave & 1) * 64;
  int l15  = lane & 15;
  int quad = lane >> 4;
  int k8   = quad * 8;

  int srow = tid >> 1;
  int scol = (tid & 1) * 16;

  const float*  Af = (const float*)Av  + (size_t)(bm + srow) * K + scol;
  const ushort* Ah = (const ushort*)Av + (size_t)(bm + srow) * K + scol;
  const ushort* Bp = Bt + (size_t)(bn + srow) * K + scol;

  floatx4 acc[4][4];
#pragma unroll
  for (int i = 0; i < 4; ++i)
#pragma unroll
    for (int j = 0; j < 4; ++j) acc[i][j] = floatx4{0,0,0,0};

  uint4 av0, av1, bv0, bv1;
  if (AF32) {
    float4 f0 = *(const float4*)Af,      f1 = *(const float4*)(Af + 4);
    float4 f2 = *(const float4*)(Af + 8), f3 = *(const float4*)(Af + 12);
    av0.x = pack_bf2(f0.x, f0.y); av0.y = pack_bf2(f0.z, f0.w);
    av0.z = pack_bf2(f1.x, f1.y); av0.w = pack_bf2(f1.z, f1.w);
    av1.x = pack_bf2(f2.x, f2.y); av1.y = pack_bf2(f2.z, f2.w);
    av1.z = pack_bf2(f3.x, f3.y); av1.w = pack_bf2(f3.z, f3.w);
  } else {
    av0 = *(const uint4*)Ah; av1 = *(const uint4*)(Ah + 8);
  }
  bv0 = *(const uint4*)Bp; bv1 = *(const uint4*)(Bp + 8);

  for (int k0 = 0; k0 < K; k0 += 32) {
    __syncthreads();
    *(uint4*)&As[srow * GKP + scol]     = av0;
    *(uint4*)&As[srow * GKP + scol + 8] = av1;
    *(uint4*)&Bs[srow * GKP + scol]     = bv0;
    *(uint4*)&Bs[srow * GKP + scol + 8] = bv1;
    __syncthreads();
    if (k0 + 32 < K) {
      Af += 32; Ah += 32; Bp += 32;
      if (AF32) {
        float4 f0 = *(const float4*)Af,      f1 = *(const float4*)(Af + 4);
        float4 f2 = *(const float4*)(Af + 8), f3 = *(const float4*)(Af + 12);
        av0.x = pack_bf2(f0.x, f0.y); av0.y = pack_bf2(f0.z, f0.w);
        av0.z = pack_bf2(f1.x, f1.y); av0.w = pack_bf2(f1.z, f1.w);
        av1.x = pack_bf2(f2.x, f2.y); av1.y = pack_bf2(f2.z, f2.w);
        av1.z = pack_bf2(f3.x, f3.y); av1.w = pack_bf2(f3.z, f3.w);
      } else {
        av0 = *(const uint4*)Ah; av1 = *(const uint4*)(Ah + 8);
      }
      bv0 = *(const uint4*)Bp; bv1 = *(const uint4*)(Bp + 8);
    }
    bf16x8 a[4], b[4];
#pragma unroll
    for (int t = 0; t < 4; ++t) {
      a[t] = *(const bf16x8*)&As[(wr + t * 16 + l15) * GKP + k8];
      b[t] = *(const bf16x8*)&Bs[(wc + t * 16 + l15) * GKP + k8];
    }
#pragma unroll
    for (int mt = 0; mt < 4; ++mt)
#pragma unroll
      for (int nt = 0; nt < 4; ++nt)
        acc[mt][nt] = __builtin_amdgcn_mfma_f32_16x16x32_bf16(a[mt], b[nt], acc[mt][nt], 0, 0, 0);
  }

#pragma unroll
  for (int mt = 0; mt < 4; ++mt)
#pragma unroll
    for (int nt = 0; nt < 4; ++nt)
#pragma unroll
      for (int r = 0; r < 4; ++r) {
        size_t idx = (size_t)(bm + wr + mt * 16 + quad * 4 + r) * N
                     + bn + wc + nt * 16 + l15;
        if (CF32) ((float*)Cv)[idx] = acc[mt][nt][r];
        else      ((ushort*)Cv)[idx] = f2bf(acc[mt][nt][r]);
      }
}

// ------- flash attention, legacy (fallback path) ----------------------------
#define QP 72
#define PP 72

__global__ __launch_bounds__(256) void gqa_attn(
    const ushort* __restrict__ q_buf,  // [B*S, DIM]
    const ushort* __restrict__ k_buf,  // [B*S, 512]
    const ushort* __restrict__ vT,     // [B, 512, S]
    ushort* __restrict__ attn)         // [B*S, DIM]
{
  __shared__ __align__(16) ushort Qs[64 * QP];
  __shared__ __align__(16) ushort Ks[64 * QP];
  __shared__ __align__(16) ushort Vs[64 * QP];
  __shared__ __align__(16) ushort Ps[4][16 * PP];  // wave-private

  int bid = blockIdx.x;
  int qt  = bid & 31;
  int g   = (bid >> 5) & 3;
  int h   = (bid >> 7) & 7;
  int b   = bid >> 10;

  int tid  = threadIdx.x;
  int wave = tid >> 6;
  int lane = tid & 63;
  int l15  = lane & 15;
  int quad = lane >> 4;
  int k8   = quad * 8;

  int srow = tid >> 2;
  int c16  = (tid & 3) * 16;

  {
    const ushort* src = q_buf + (size_t)(b * SEQ + qt * 64 + srow) * DIM
                        + (h * NGRP + g) * HDIM + c16;
    *(uint4*)&Qs[srow * QP + c16]     = *(const uint4*)src;
    *(uint4*)&Qs[srow * QP + c16 + 8] = *(const uint4*)(src + 8);
  }
  __syncthreads();

  bf16x8 bq0 = *(const bf16x8*)&Qs[(wave * 16 + l15) * QP + k8];
  bf16x8 bq1 = *(const bf16x8*)&Qs[(wave * 16 + l15) * QP + 32 + k8];

  float lpart = 0.f;
  floatx4 oarr[4] = {{0,0,0,0},{0,0,0,0},{0,0,0,0},{0,0,0,0}};

  const ushort* kp = k_buf + (size_t)(b * SEQ + srow) * KVDIM + h * HDIM + c16;
  const ushort* vp = vT + ((size_t)(b * NKV + h) * HDIM + srow) * SEQ + c16;

  uint4 kv0 = *(const uint4*)kp;
  uint4 kv1 = *(const uint4*)(kp + 8);
  uint4 vv0 = *(const uint4*)vp;
  uint4 vv1 = *(const uint4*)(vp + 8);

  ushort* Pw = &Ps[wave][0];

  for (int kt = 0; kt < SEQ / 64; ++kt) {
    __syncthreads();
    *(uint4*)&Ks[srow * QP + c16]     = kv0;
    *(uint4*)&Ks[srow * QP + c16 + 8] = kv1;
    *(uint4*)&Vs[srow * QP + c16]     = vv0;
    *(uint4*)&Vs[srow * QP + c16 + 8] = vv1;
    __syncthreads();
    if (kt + 1 < SEQ / 64) {
      kp += (size_t)64 * KVDIM;
      vp += 64;
      kv0 = *(const uint4*)kp;
      kv1 = *(const uint4*)(kp + 8);
      vv0 = *(const uint4*)vp;
      vv1 = *(const uint4*)(vp + 8);
    }

    floatx4 sarr[4];
#pragma unroll
    for (int nt = 0; nt < 4; ++nt) {
      bf16x8 ak0 = *(const bf16x8*)&Ks[(nt * 16 + l15) * QP + k8];
      bf16x8 ak1 = *(const bf16x8*)&Ks[(nt * 16 + l15) * QP + 32 + k8];
      floatx4 s = {0.f, 0.f, 0.f, 0.f};
      s = __builtin_amdgcn_mfma_f32_16x16x32_bf16(ak0, bq0, s, 0, 0, 0);
      s = __builtin_amdgcn_mfma_f32_16x16x32_bf16(ak1, bq1, s, 0, 0, 0);
      sarr[nt] = s;
    }

#pragma unroll
    for (int nt = 0; nt < 4; ++nt) {
      float p0 = __expf(sarr[nt][0] * 0.125f);
      float p1 = __expf(sarr[nt][1] * 0.125f);
      float p2 = __expf(sarr[nt][2] * 0.125f);
      float p3 = __expf(sarr[nt][3] * 0.125f);
      lpart += (p0 + p1) + (p2 + p3);
      uint2 pw;
      pw.x = pack_bf2(p0, p1);
      pw.y = pack_bf2(p2, p3);
      *(uint2*)&Pw[l15 * PP + nt * 16 + quad * 4] = pw;
    }

    bf16x8 ap0 = *(const bf16x8*)&Pw[l15 * PP + k8];
    bf16x8 ap1 = *(const bf16x8*)&Pw[l15 * PP + 32 + k8];
#pragma unroll
    for (int dt = 0; dt < 4; ++dt) {
      bf16x8 bv0q = *(const bf16x8*)&Vs[(dt * 16 + l15) * QP + k8];
      bf16x8 bv1q = *(const bf16x8*)&Vs[(dt * 16 + l15) * QP + 32 + k8];
      oarr[dt] = __builtin_amdgcn_mfma_f32_16x16x32_bf16(ap0, bv0q, oarr[dt], 0, 0, 0);
      oarr[dt] = __builtin_amdgcn_mfma_f32_16x16x32_bf16(ap1, bv1q, oarr[dt], 0, 0, 0);
    }
  }

  float ls = lpart;
  ls += __shfl_xor(ls, 16, 64);
  ls += __shfl_xor(ls, 32, 64);

  __syncthreads();
  float* Lw = (float*)Pw;
  if (quad == 0) Lw[l15] = ls;
  __syncthreads();

#pragma unroll
  for (int r = 0; r < 4; ++r) {
    float inv = 1.0f / Lw[quad * 4 + r];
    int q = qt * 64 + wave * 16 + quad * 4 + r;
    size_t rowoff = (size_t)(b * SEQ + q) * DIM + (h * NGRP + g) * HDIM;
#pragma unroll
    for (int dt = 0; dt < 4; ++dt)
      attn[rowoff + dt * 16 + l15] = f2bf(oarr[dt][r] * inv);
  }
}

// ------- flash attention v3c: g-fused, VALU-lean softmax (FROZEN, round 6) --
__global__ __launch_bounds__(256, 2) void gqa_attn3(
    const ushort* __restrict__ qkv,  // [B*S, 3072] : q[0,2048) k[2048,2560) v[2560,3072)
    const ushort* __restrict__ vT,   // [B, 512, S]
    ushort* __restrict__ attn)       // [B*S, DIM]
{
  __shared__ __align__(16) ushort Ks[64 * QP];     // 9216 B
  __shared__ __align__(16) ushort Vs[64 * QP];     // 9216 B
  __shared__ __align__(16) ushort Ps[4][16 * PP];  // 9216 B, wave-private

  int bid = blockIdx.x;
  int qt  = bid & 31;          // 32 q-tiles of 64 rows
  int h   = (bid >> 5) & 7;
  int b   = bid >> 8;

  int tid  = threadIdx.x;
  int wave = tid >> 6;
  int lane = tid & 63;
  int l15  = lane & 15;
  int quad = lane >> 4;
  int k8   = quad * 8;

  int srow = tid >> 2;
  int c16  = (tid & 3) * 16;

  // Q fragments for all 4 g's, loaded once and pre-scaled by 0.125 (exact)
  bf16x8 bq[NGRP][2];
  {
    const ushort* qrow = qkv + (size_t)(b * SEQ + qt * 64 + wave * 16 + l15) * QKVD
                         + h * NGRP * HDIM;
#pragma unroll
    for (int g = 0; g < NGRP; ++g) {
      bq[g][0] = *(const bf16x8*)(qrow + g * HDIM + k8);
      bq[g][1] = *(const bf16x8*)(qrow + g * HDIM + 32 + k8);
    }
  }
#pragma unroll
  for (int g = 0; g < NGRP; ++g)
#pragma unroll
    for (int j = 0; j < 2; ++j)
#pragma unroll
      for (int e = 0; e < 8; ++e)
        bq[g][j][e] = (__bf16)((float)bq[g][j][e] * 0.125f);

  bf16x8 vones;
#pragma unroll
  for (int i = 0; i < 8; ++i) vones[i] = (__bf16)1.0f;

  floatx4 lacc[NGRP];
  floatx4 oacc[NGRP][4];
#pragma unroll
  for (int g = 0; g < NGRP; ++g) {
    lacc[g] = floatx4{0,0,0,0};
#pragma unroll
    for (int dt = 0; dt < 4; ++dt) oacc[g][dt] = floatx4{0,0,0,0};
  }

  const ushort* kp = qkv + (size_t)(b * SEQ + srow) * QKVD + DIM + h * HDIM + c16;
  const ushort* vp = vT + ((size_t)(b * NKV + h) * HDIM + srow) * SEQ + c16;

  uint4 kv0 = *(const uint4*)kp;
  uint4 kv1 = *(const uint4*)(kp + 8);
  uint4 vv0 = *(const uint4*)vp;
  uint4 vv1 = *(const uint4*)(vp + 8);

  ushort* Pw = &Ps[wave][0];

  for (int kt = 0; kt < SEQ / 64; ++kt) {
    __syncthreads();
    *(uint4*)&Ks[srow * QP + c16]     = kv0;
    *(uint4*)&Ks[srow * QP + c16 + 8] = kv1;
    *(uint4*)&Vs[srow * QP + c16]     = vv0;
    *(uint4*)&Vs[srow * QP + c16 + 8] = vv1;
    __syncthreads();
    if (kt + 1 < SEQ / 64) {
      kp += (size_t)64 * QKVD;
      vp += 64;
      kv0 = *(const uint4*)kp;
      kv1 = *(const uint4*)(kp + 8);
      vv0 = *(const uint4*)vp;
      vv1 = *(const uint4*)(vp + 8);
    }

    // hoist K/V fragments to registers ONCE per tile (shared by all g)
    bf16x8 ak[4][2], av[4][2];
#pragma unroll
    for (int t = 0; t < 4; ++t) {
      ak[t][0] = *(const bf16x8*)&Ks[(t * 16 + l15) * QP + k8];
      ak[t][1] = *(const bf16x8*)&Ks[(t * 16 + l15) * QP + 32 + k8];
      av[t][0] = *(const bf16x8*)&Vs[(t * 16 + l15) * QP + k8];
      av[t][1] = *(const bf16x8*)&Vs[(t * 16 + l15) * QP + 32 + k8];
    }

#pragma unroll
    for (int g = 0; g < NGRP; ++g) {
      // --- S^T = K . Q^T for group g : lane holds 16 keys for q = l15 ---
#pragma unroll
      for (int nt = 0; nt < 4; ++nt) {
        floatx4 s = {0.f, 0.f, 0.f, 0.f};
        s = __builtin_amdgcn_mfma_f32_16x16x32_bf16(ak[nt][0], bq[g][0], s, 0, 0, 0);
        s = __builtin_amdgcn_mfma_f32_16x16x32_bf16(ak[nt][1], bq[g][1], s, 0, 0, 0);
        float p0 = __expf(s[0]);
        float p1 = __expf(s[1]);
        float p2 = __expf(s[2]);
        float p3 = __expf(s[3]);
        uint2 pw;
        pw.x = pack_bf2_rn(p0, p1);
        pw.y = pack_bf2_rn(p2, p3);
        *(uint2*)&Pw[l15 * PP + nt * 16 + quad * 4] = pw;
      }

      // fence: order P writes (uint2) before P reads (bf16x8) — distinct TBAA
      // types, compiler must not reorder; DS is in-order per wave in HW.
      asm volatile("" ::: "memory");

      bf16x8 ap0 = *(const bf16x8*)&Pw[l15 * PP + k8];
      bf16x8 ap1 = *(const bf16x8*)&Pw[l15 * PP + 32 + k8];
      // l[q] = sum_k P[q][k] via MFMA against ones (all output cols equal)
      lacc[g] = __builtin_amdgcn_mfma_f32_16x16x32_bf16(ap0, vones, lacc[g], 0, 0, 0);
      lacc[g] = __builtin_amdgcn_mfma_f32_16x16x32_bf16(ap1, vones, lacc[g], 0, 0, 0);
#pragma unroll
      for (int dt = 0; dt < 4; ++dt) {
        oacc[g][dt] = __builtin_amdgcn_mfma_f32_16x16x32_bf16(ap0, av[dt][0], oacc[g][dt], 0, 0, 0);
        oacc[g][dt] = __builtin_amdgcn_mfma_f32_16x16x32_bf16(ap1, av[dt][1], oacc[g][dt], 0, 0, 0);
      }

      // fence: order this g's P reads before next g's P writes (WAR)
      asm volatile("" ::: "memory");
    }
  }

  // epilogue: lacc[g][r] = l[q = quad*4+r] in every lane — no cross-lane comm
#pragma unroll
  for (int g = 0; g < NGRP; ++g) {
#pragma unroll
    for (int r = 0; r < 4; ++r) {
      float inv = 1.0f / lacc[g][r];
      int q = qt * 64 + wave * 16 + quad * 4 + r;
      size_t rowoff = (size_t)(b * SEQ + q) * DIM + (h * NGRP + g) * HDIM;
#pragma unroll
      for (int dt = 0; dt < 4; ++dt)
        attn[rowoff + dt * 16 + l15] = f2bf(oacc[g][dt][r] * inv);
    }
  }
}

// ---------------- launch ----------------------------------------------------
extern "C" void kernel_launch(void* const* d_in, const int* in_sizes, int n_in,
                              void* d_out, int out_size, void* d_ws, size_t ws_size,
                              hipStream_t stream)
{
  (void)in_sizes; (void)n_in; (void)out_size;
  const float* x  = (const float*)d_in[0];
  const float* Wq = (const float*)d_in[1];
  const float* Wk = (const float*)d_in[2];
  const float* Wv = (const float*)d_in[3];
  const float* Wo = (const float*)d_in[4];
  float*  outf = (float*)d_out;
  ushort* ob   = (ushort*)d_out;
  ushort* ws16 = (ushort*)d_ws;

  const size_t Mi = 1024 * 1024;
  dim3 blk(256);
  const int M = BATCH * SEQ;

  if (ws_size >= 40u * Mi) {
    // ---- main path: fused QKV projection (+V^T epilogue) + g-fused attn ----
    // ws (Mi ushorts): WqkvT[0,6) = WqT|WkT|WvT as [3072,2048]; WoT[8,12);
    //                  xb[12,20) -> ao[12,20) after projection
    // d_out scratch:   qkv[0,12) = [4096,3072]; vt[12,14)
    ushort* WqkvT = ws16;
    ushort* WoT   = ws16 + 8 * Mi;
    ushort* xb    = ws16 + 12 * Mi;
    ushort* ao    = ws16 + 12 * Mi;   // overlays xb (dead after projection)
    ushort* qkv   = ob;
    ushort* vt    = ob + 12 * Mi;

    // one prep launch: x->bf16 (blocks 0..4095) + all weight transposes
    prep_all<<<dim3(4096 + 2560), blk, 0, stream>>>(x, Wq, Wk, Wv, Wo, xb, WqkvT, WoT);

    // one GEMM for q|k|v; V-region blocks also emit V^T directly into vt
    gemm_lds<false><<<dim3(QKVD / 128, M / 128), blk, 0, stream>>>(
        xb, WqkvT, qkv, vt, M, QKVD, DIM);

    gqa_attn3<<<dim3(BATCH * NKV * (SEQ / 64)), blk, 0, stream>>>(qkv, vt, ao);

    gemm_lds<true><<<dim3(DIM / 128, M / 128), blk, 0, stream>>>(
        ao, WoT, outf, nullptr, M, DIM, DIM);
  } else {
    // ---- fallback: round-4 structure (proven, ws <= 24 MiB) ----
    ushort* qb  = ob;
    ushort* kb  = ob + 8 * Mi;
    ushort* vb  = ob + 10 * Mi;
    ushort* vt  = ob + 12 * Mi;
    ushort* WqT = ws16;
    ushort* WkT = ws16 + 4 * Mi;
    ushort* WvT = ws16 + 5 * Mi;
    ushort* WoT = ws16 + 8 * Mi;
    ushort* ao  = ws16;

    transpose_f2b<<<dim3(DIM / 64,   DIM / 64), blk, 0, stream>>>(Wq, WqT, DIM, DIM);
    transpose_f2b<<<dim3(KVDIM / 64, DIM / 64), blk, 0, stream>>>(Wk, WkT, DIM, KVDIM);
    transpose_f2b<<<dim3(KVDIM / 64, DIM / 64), blk, 0, stream>>>(Wv, WvT, DIM, KVDIM);
    transpose_f2b<<<dim3(DIM / 64,   DIM / 64), blk, 0, stream>>>(Wo, WoT, DIM, DIM);

    gemm128<true, false><<<dim3(DIM / 128, M / 128), blk, 0, stream>>>(x, WqT, qb, M, DIM, DIM);
    gemm_abt<true, false><<<dim3(KVDIM / BN, M / BM), blk, 0, stream>>>(x, WkT, kb, M, KVDIM, DIM);
    gemm_abt<true, false><<<dim3(KVDIM / BN, M / BM), blk, 0, stream>>>(x, WvT, vb, M, KVDIM, DIM);

    transpose_b2b<<<dim3(KVDIM / 64, SEQ / 64, BATCH), blk, 0, stream>>>(
        vb, vt, SEQ, KVDIM, KVDIM, (size_t)SEQ * KVDIM, (size_t)KVDIM * SEQ);

    gqa_attn<<<dim3(BATCH * NKV * NGRP * (SEQ / 64)), blk, 0, stream>>>(qb, kb, vt, ao);

    gemm128<false, true><<<dim3(DIM / 128, M / 128), blk, 0, stream>>>(ao, WoT, outf, M, DIM, DIM);
  }
}

// Round 11
// 307.025 us; speedup vs baseline: 1.0715x; 1.0087x over previous
//
#include <hip/hip_runtime.h>
#include <hip/hip_bf16.h>

typedef __bf16 bf16x8 __attribute__((ext_vector_type(8)));
typedef float floatx4 __attribute__((ext_vector_type(4)));

#define DIM   2048
#define SEQ   2048
#define BATCH 2
#define NKV   8
#define NGRP  4
#define HDIM  64
#define KVDIM (NKV * HDIM)   // 512
#define QKVD  3072           // fused q|k|v projection width

__device__ __forceinline__ ushort f2bf(float f) {          // RNE
  union { float f; unsigned u; } x; x.f = f;
  return (ushort)((x.u + 0x7fffu + ((x.u >> 16) & 1u)) >> 16);
}
// pack two floats -> two bf16 in one u32 (round-half-up, bit trick)
__device__ __forceinline__ unsigned pack_bf2(float a, float b) {
  union { float f; unsigned u; } x, y; x.f = a; y.f = b;
  unsigned ua = x.u + 0x8000u, ub = y.u + 0x8000u;
  return __builtin_amdgcn_perm(ub, ua, 0x07060302);
}
// pack two floats -> two bf16 (RNE) via bit ops
__device__ __forceinline__ unsigned pack_bf2_rne(float a, float b) {
  return (unsigned)f2bf(a) | ((unsigned)f2bf(b) << 16);
}
// pack two floats -> two bf16 in one u32 via v_cvt_pk_bf16_f32 (RNE, 1 instr)
__device__ __forceinline__ unsigned pack_bf2_rn(float a, float b) {
  __hip_bfloat162 h = __float22bfloat162_rn(make_float2(a, b));
  union { __hip_bfloat162 h; unsigned u; } cv; cv.h = h; return cv.u;
}

typedef const __attribute__((address_space(1))) void* gas_t;
typedef __attribute__((address_space(3))) void* las_t;
__device__ __forceinline__ void gload_lds16(const ushort* g, ushort* l) {
  __builtin_amdgcn_global_load_lds((gas_t)g, (las_t)l, 16, 0, 0);
}

// ------- x fp32 -> bf16 bulk convert (fallback body) -------------------------
__global__ __launch_bounds__(256) void cvt_f2b(
    const float* __restrict__ in, ushort* __restrict__ out)
{
  int i = blockIdx.x * 256 + threadIdx.x;     // one uint4 (8 bf16) per thread
  const float4* p = (const float4*)in + (size_t)i * 2;
  float4 f0 = p[0], f1 = p[1];
  uint4 v;
  v.x = pack_bf2(f0.x, f0.y); v.y = pack_bf2(f0.z, f0.w);
  v.z = pack_bf2(f1.x, f1.y); v.w = pack_bf2(f1.z, f1.w);
  ((uint4*)out)[i] = v;
}

// ------- transpose + convert: fp32 [R,C] -> bf16 [C,R] (weights) ------------
__global__ __launch_bounds__(256) void transpose_f2b(
    const float* __restrict__ in, ushort* __restrict__ out, int R, int C)
{
  __shared__ ushort tileT[64][72];
  int tr = blockIdx.y * 64;
  int tc = blockIdx.x * 64;
  int row = threadIdx.x >> 2;
  int c16 = (threadIdx.x & 3) * 16;

  ushort arr[16];
  const float* src = in + (size_t)(tr + row) * C + tc + c16;
#pragma unroll
  for (int q = 0; q < 4; ++q) {
    float4 f = *(const float4*)(src + q * 4);
    arr[q * 4 + 0] = f2bf(f.x); arr[q * 4 + 1] = f2bf(f.y);
    arr[q * 4 + 2] = f2bf(f.z); arr[q * 4 + 3] = f2bf(f.w);
  }
  int rot = row & 15;
#pragma unroll
  for (int j = 0; j < 16; ++j) {
    int i2 = (j + rot) & 15;
    tileT[c16 + i2][row] = arr[i2];
  }
  __syncthreads();
  ushort* dst = out + (size_t)(tc + row) * R + tr + c16;
  *(uint4*)dst       = *(const uint4*)&tileT[row][c16];
  *(uint4*)(dst + 8) = *(const uint4*)&tileT[row][c16 + 8];
}

// ------- fused prep: x convert (blocks 0..4095) + 4 weight transposes -------
__global__ __launch_bounds__(256) void prep_all(
    const float* __restrict__ x,
    const float* __restrict__ Wq, const float* __restrict__ Wk,
    const float* __restrict__ Wv, const float* __restrict__ Wo,
    ushort* __restrict__ xb, ushort* __restrict__ WqkvT, ushort* __restrict__ WoT)
{
  __shared__ ushort tileT[64][72];
  int bid = blockIdx.x;
  if (bid < 4096) {                 // ---- cvt: x fp32 -> bf16 ----
    int i = bid * 256 + threadIdx.x;
    const float4* p = (const float4*)x + (size_t)i * 2;
    float4 f0 = p[0], f1 = p[1];
    uint4 v;
    v.x = pack_bf2(f0.x, f0.y); v.y = pack_bf2(f0.z, f0.w);
    v.z = pack_bf2(f1.x, f1.y); v.w = pack_bf2(f1.z, f1.w);
    ((uint4*)xb)[i] = v;
    return;
  }
  // ---- weight transposes ----
  const size_t Mi = 1024 * 1024;
  int id = bid - 4096;
  const float* in; ushort* out; int C;
  if (id < 1024)      { in = Wq; out = WqkvT;          C = 2048; }
  else if (id < 1280) { in = Wk; out = WqkvT + 4 * Mi; C = 512;  id -= 1024; }
  else if (id < 1536) { in = Wv; out = WqkvT + 5 * Mi; C = 512;  id -= 1280; }
  else                { in = Wo; out = WoT;            C = 2048; id -= 1536; }
  const int R = 2048;
  int nbx = C / 64;
  int tr = (id / nbx) * 64;
  int tc = (id % nbx) * 64;
  int row = threadIdx.x >> 2;
  int c16 = (threadIdx.x & 3) * 16;

  ushort arr[16];
  const float* src = in + (size_t)(tr + row) * C + tc + c16;
#pragma unroll
  for (int q = 0; q < 4; ++q) {
    float4 f = *(const float4*)(src + q * 4);
    arr[q * 4 + 0] = f2bf(f.x); arr[q * 4 + 1] = f2bf(f.y);
    arr[q * 4 + 2] = f2bf(f.z); arr[q * 4 + 3] = f2bf(f.w);
  }
  int rot = row & 15;
#pragma unroll
  for (int j = 0; j < 16; ++j) {
    int i2 = (j + rot) & 15;
    tileT[c16 + i2][row] = arr[i2];
  }
  __syncthreads();
  ushort* dst = out + (size_t)(tc + row) * R + tr + c16;
  *(uint4*)dst       = *(const uint4*)&tileT[row][c16];
  *(uint4*)(dst + 8) = *(const uint4*)&tileT[row][c16 + 8];
}

// ------- transpose bf16 [R,C] (strided rows) -> bf16 [C,R], batched ---------
// (fallback path only; main path fuses V^T into the QKV GEMM epilogue)
__global__ __launch_bounds__(256) void transpose_b2b(
    const ushort* __restrict__ in, ushort* __restrict__ out,
    int R, int C, int in_stride, size_t in_batch, size_t out_batch)
{
  __shared__ ushort tileT[64][72];
  in  += (size_t)blockIdx.z * in_batch;
  out += (size_t)blockIdx.z * out_batch;
  int tr = blockIdx.y * 64;
  int tc = blockIdx.x * 64;
  int row = threadIdx.x >> 2;
  int c16 = (threadIdx.x & 3) * 16;

  ushort arr[16];
  const ushort* src = in + (size_t)(tr + row) * in_stride + tc + c16;
  *(uint4*)&arr[0] = *(const uint4*)src;
  *(uint4*)&arr[8] = *(const uint4*)(src + 8);
  int rot = row & 15;
#pragma unroll
  for (int j = 0; j < 16; ++j) {
    int i2 = (j + rot) & 15;
    tileT[c16 + i2][row] = arr[i2];
  }
  __syncthreads();
  ushort* dst = out + (size_t)(tc + row) * R + tr + c16;
  *(uint4*)dst       = *(const uint4*)&tileT[row][c16];
  *(uint4*)(dst + 8) = *(const uint4*)&tileT[row][c16 + 8];
}

// ------- 2-phase m97 GEMM (round-8/10 proven): C = A @ Bt^T, bf16 -----------
// 128x128 tile, BK=32 double-buffered (32 KB LDS). barrier -> issue
// STAGE(buf^1, t+1) -> compute buf[cur]. One barrier per K-step.
// XCD-aware block swizzle (bijective when nwg%8==0).
// vtOut != nullptr (QKV call): V-region blocks (bn >= 2560) additionally
// write V^T into vt from the accumulators (bit-identical to a transpose of
// the rounded C output).
template<bool CF32>
__global__ __launch_bounds__(256) void gemm_lds(
    const ushort* __restrict__ A, const ushort* __restrict__ Bt,
    void* __restrict__ Cv, ushort* __restrict__ vtOut, int M, int N, int K)
{
  __shared__ ushort As[2][128 * 32];   // 8 KB each
  __shared__ ushort Bs[2][128 * 32];
  int tid  = threadIdx.x;

  int gx  = gridDim.x;
  int nwg = gx * gridDim.y;
  int lin = blockIdx.y * gx + blockIdx.x;
  if ((nwg & 7) == 0) {                 // XCD swizzle, bijective
    int cpx = nwg >> 3;
    lin = (lin & 7) * cpx + (lin >> 3);
  }
  int bm = (lin / gx) * 128;
  int bn = (lin % gx) * 128;

  int wv   = tid >> 6;
  int ln   = tid & 63;
  int wr   = (wv >> 1) * 64;
  int wc   = (wv & 1) * 64;
  int l15  = ln & 15;
  int quad = ln >> 4;

  int r4 = ln >> 2;
  int c8 = (ln & 3) * 8;
  const ushort* Ag0 = A  + (size_t)(bm + 32 * wv +      r4) * K + c8;
  const ushort* Ag1 = A  + (size_t)(bm + 32 * wv + 16 + r4) * K + c8;
  const ushort* Bg0 = Bt + (size_t)(bn + 32 * wv +      r4) * K + c8;
  const ushort* Bg1 = Bt + (size_t)(bn + 32 * wv + 16 + r4) * K + c8;
  int st0 = 1024 * wv +       ln * 8;
  int st1 = 1024 * wv + 512 + ln * 8;

  floatx4 acc[4][4];
#pragma unroll
  for (int i = 0; i < 4; ++i)
#pragma unroll
    for (int j = 0; j < 4; ++j) acc[i][j] = floatx4{0,0,0,0};

  // prologue: stage K-step 0 into buf 0
  gload_lds16(Ag0, &As[0][0] + st0);
  gload_lds16(Ag1, &As[0][0] + st1);
  gload_lds16(Bg0, &Bs[0][0] + st0);
  gload_lds16(Bg1, &Bs[0][0] + st1);
  Ag0 += 32; Ag1 += 32; Bg0 += 32; Bg1 += 32;

  int cur = 0;
  for (int k0 = 0; k0 < K; k0 += 32) {
    __syncthreads();        // drains vmcnt(0): buf[cur] ready
    if (k0 + 32 < K) {      // issue next-tile stage BEFORE compute (overlap)
      ushort* Ad = &As[cur ^ 1][0];
      ushort* Bd = &Bs[cur ^ 1][0];
      gload_lds16(Ag0, Ad + st0);
      gload_lds16(Ag1, Ad + st1);
      gload_lds16(Bg0, Bd + st0);
      gload_lds16(Bg1, Bd + st1);
      Ag0 += 32; Ag1 += 32; Bg0 += 32; Bg1 += 32;
    }

    bf16x8 a[4], b[4];
#pragma unroll
    for (int t = 0; t < 4; ++t) {
      a[t] = *(const bf16x8*)&As[cur][(wr + t * 16 + l15) * 32 + quad * 8];
      b[t] = *(const bf16x8*)&Bs[cur][(wc + t * 16 + l15) * 32 + quad * 8];
    }
#pragma unroll
    for (int mt = 0; mt < 4; ++mt)
#pragma unroll
      for (int nt = 0; nt < 4; ++nt)
        acc[mt][nt] = __builtin_amdgcn_mfma_f32_16x16x32_bf16(a[mt], b[nt], acc[mt][nt], 0, 0, 0);
    cur ^= 1;
  }

#pragma unroll
  for (int mt = 0; mt < 4; ++mt)
#pragma unroll
    for (int nt = 0; nt < 4; ++nt)
#pragma unroll
      for (int r = 0; r < 4; ++r) {
        size_t idx = (size_t)(bm + wr + mt * 16 + quad * 4 + r) * N
                     + bn + wc + nt * 16 + l15;
        if (CF32) ((float*)Cv)[idx] = acc[mt][nt][r];
        else      ((ushort*)Cv)[idx] = f2bf(acc[mt][nt][r]);
      }

  // fused V^T output (QKV call only; V-region blocks are bn>=2560 exactly)
  if (!CF32 && vtOut != nullptr && bn >= 2560) {
    int bb   = bm >> 11;               // batch (128-row tiles never straddle)
    int base = (bm & 2047) + wr;       // seq base of this wave
#pragma unroll
    for (int mt = 0; mt < 4; ++mt)
#pragma unroll
      for (int nt = 0; nt < 4; ++nt) {
        int c   = bn + wc + nt * 16 + l15 - 2560;       // vt column (0..511)
        int seq = base + mt * 16 + quad * 4;            // 4 consecutive rows
        ushort* vp = vtOut + ((size_t)bb * KVDIM + c) * SEQ + seq;
        *(unsigned*)(vp)     = pack_bf2_rne(acc[mt][nt][0], acc[mt][nt][1]);
        *(unsigned*)(vp + 2) = pack_bf2_rne(acc[mt][nt][2], acc[mt][nt][3]);
      }
  }
}

// ------- legacy GEMMs (fallback path) ---------------------------------------
#define BM 64
#define BN 64
#define BK 32
#define KP 40

template<bool AF32, bool CF32>
__global__ __launch_bounds__(256) void gemm_abt(
    const void* __restrict__ Av, const ushort* __restrict__ Bt,
    void* __restrict__ Cv, int M, int N, int K)
{
  __shared__ ushort As[BM * KP];
  __shared__ ushort Bs[BN * KP];
  int tid  = threadIdx.x;
  int bm   = blockIdx.y * BM;
  int bn   = blockIdx.x * BN;
  int wave = tid >> 6;
  int lane = tid & 63;
  int wr   = (wave >> 1) * 32;
  int wc   = (wave & 1) * 32;
  int l15  = lane & 15;
  int k8   = (lane >> 4) * 8;

  int srow = tid >> 2;
  int scol = (tid & 3) * 8;

  const float*  Af = (const float*)Av  + (size_t)(bm + srow) * K + scol;
  const ushort* Ah = (const ushort*)Av + (size_t)(bm + srow) * K + scol;
  const ushort* Bp = Bt + (size_t)(bn + srow) * K + scol;

  floatx4 acc00 = {0,0,0,0}, acc01 = {0,0,0,0}, acc10 = {0,0,0,0}, acc11 = {0,0,0,0};

  uint4 av, bv;
  if (AF32) {
    float4 f0 = *(const float4*)Af;
    float4 f1 = *(const float4*)(Af + 4);
    av.x = pack_bf2(f0.x, f0.y); av.y = pack_bf2(f0.z, f0.w);
    av.z = pack_bf2(f1.x, f1.y); av.w = pack_bf2(f1.z, f1.w);
  } else {
    av = *(const uint4*)Ah;
  }
  bv = *(const uint4*)Bp;

  for (int k0 = 0; k0 < K; k0 += BK) {
    __syncthreads();
    *(uint4*)&As[srow * KP + scol] = av;
    *(uint4*)&Bs[srow * KP + scol] = bv;
    __syncthreads();
    if (k0 + BK < K) {
      Af += BK; Ah += BK; Bp += BK;
      if (AF32) {
        float4 f0 = *(const float4*)Af;
        float4 f1 = *(const float4*)(Af + 4);
        av.x = pack_bf2(f0.x, f0.y); av.y = pack_bf2(f0.z, f0.w);
        av.z = pack_bf2(f1.x, f1.y); av.w = pack_bf2(f1.z, f1.w);
      } else {
        av = *(const uint4*)Ah;
      }
      bv = *(const uint4*)Bp;
    }
    bf16x8 a0 = *(const bf16x8*)&As[(wr +      l15) * KP + k8];
    bf16x8 a1 = *(const bf16x8*)&As[(wr + 16 + l15) * KP + k8];
    bf16x8 b0 = *(const bf16x8*)&Bs[(wc +      l15) * KP + k8];
    bf16x8 b1 = *(const bf16x8*)&Bs[(wc + 16 + l15) * KP + k8];
    acc00 = __builtin_amdgcn_mfma_f32_16x16x32_bf16(a0, b0, acc00, 0, 0, 0);
    acc01 = __builtin_amdgcn_mfma_f32_16x16x32_bf16(a0, b1, acc01, 0, 0, 0);
    acc10 = __builtin_amdgcn_mfma_f32_16x16x32_bf16(a1, b0, acc10, 0, 0, 0);
    acc11 = __builtin_amdgcn_mfma_f32_16x16x32_bf16(a1, b1, acc11, 0, 0, 0);
  }

  int rbase = (lane >> 4) * 4;
#pragma unroll
  for (int r = 0; r < 4; ++r) {
    size_t row0 = (size_t)(bm + wr +      rbase + r) * N + bn + wc;
    size_t row1 = (size_t)(bm + wr + 16 + rbase + r) * N + bn + wc;
    if (CF32) {
      float* C = (float*)Cv;
      C[row0 +      l15] = acc00[r];
      C[row0 + 16 + l15] = acc01[r];
      C[row1 +      l15] = acc10[r];
      C[row1 + 16 + l15] = acc11[r];
    } else {
      ushort* C = (ushort*)Cv;
      C[row0 +      l15] = f2bf(acc00[r]);
      C[row0 + 16 + l15] = f2bf(acc01[r]);
      C[row1 +      l15] = f2bf(acc10[r]);
      C[row1 + 16 + l15] = f2bf(acc11[r]);
    }
  }
}

#define GKP 40
template<bool AF32, bool CF32>
__global__ __launch_bounds__(256) void gemm128(
    const void* __restrict__ Av, const ushort* __restrict__ Bt,
    void* __restrict__ Cv, int M, int N, int K)
{
  __shared__ ushort As[128 * GKP];
  __shared__ ushort Bs[128 * GKP];
  int tid  = threadIdx.x;
  int bm   = blockIdx.y * 128;
  int bn   = blockIdx.x * 128;
  int wave = tid >> 6;
  int lane = tid & 63;
  int wr   = (wave >> 1) * 64;
  int wc   = (wave & 1) * 64;
  int l15  = lane & 15;
  int quad = lane >> 4;
  int k8   = quad * 8;

  int srow = tid >> 1;
  int scol = (tid & 1) * 16;

  const float*  Af = (const float*)Av  + (size_t)(bm + srow) * K + scol;
  const ushort* Ah = (const ushort*)Av + (size_t)(bm + srow) * K + scol;
  const ushort* Bp = Bt + (size_t)(bn + srow) * K + scol;

  floatx4 acc[4][4];
#pragma unroll
  for (int i = 0; i < 4; ++i)
#pragma unroll
    for (int j = 0; j < 4; ++j) acc[i][j] = floatx4{0,0,0,0};

  uint4 av0, av1, bv0, bv1;
  if (AF32) {
    float4 f0 = *(const float4*)Af,      f1 = *(const float4*)(Af + 4);
    float4 f2 = *(const float4*)(Af + 8), f3 = *(const float4*)(Af + 12);
    av0.x = pack_bf2(f0.x, f0.y); av0.y = pack_bf2(f0.z, f0.w);
    av0.z = pack_bf2(f1.x, f1.y); av0.w = pack_bf2(f1.z, f1.w);
    av1.x = pack_bf2(f2.x, f2.y); av1.y = pack_bf2(f2.z, f2.w);
    av1.z = pack_bf2(f3.x, f3.y); av1.w = pack_bf2(f3.z, f3.w);
  } else {
    av0 = *(const uint4*)Ah; av1 = *(const uint4*)(Ah + 8);
  }
  bv0 = *(const uint4*)Bp; bv1 = *(const uint4*)(Bp + 8);

  for (int k0 = 0; k0 < K; k0 += 32) {
    __syncthreads();
    *(uint4*)&As[srow * GKP + scol]     = av0;
    *(uint4*)&As[srow * GKP + scol + 8] = av1;
    *(uint4*)&Bs[srow * GKP + scol]     = bv0;
    *(uint4*)&Bs[srow * GKP + scol + 8] = bv1;
    __syncthreads();
    if (k0 + 32 < K) {
      Af += 32; Ah += 32; Bp += 32;
      if (AF32) {
        float4 f0 = *(const float4*)Af,      f1 = *(const float4*)(Af + 4);
        float4 f2 = *(const float4*)(Af + 8), f3 = *(const float4*)(Af + 12);
        av0.x = pack_bf2(f0.x, f0.y); av0.y = pack_bf2(f0.z, f0.w);
        av0.z = pack_bf2(f1.x, f1.y); av0.w = pack_bf2(f1.z, f1.w);
        av1.x = pack_bf2(f2.x, f2.y); av1.y = pack_bf2(f2.z, f2.w);
        av1.z = pack_bf2(f3.x, f3.y); av1.w = pack_bf2(f3.z, f3.w);
      } else {
        av0 = *(const uint4*)Ah; av1 = *(const uint4*)(Ah + 8);
      }
      bv0 = *(const uint4*)Bp; bv1 = *(const uint4*)(Bp + 8);
    }
    bf16x8 a[4], b[4];
#pragma unroll
    for (int t = 0; t < 4; ++t) {
      a[t] = *(const bf16x8*)&As[(wr + t * 16 + l15) * GKP + k8];
      b[t] = *(const bf16x8*)&Bs[(wc + t * 16 + l15) * GKP + k8];
    }
#pragma unroll
    for (int mt = 0; mt < 4; ++mt)
#pragma unroll
      for (int nt = 0; nt < 4; ++nt)
        acc[mt][nt] = __builtin_amdgcn_mfma_f32_16x16x32_bf16(a[mt], b[nt], acc[mt][nt], 0, 0, 0);
  }

#pragma unroll
  for (int mt = 0; mt < 4; ++mt)
#pragma unroll
    for (int nt = 0; nt < 4; ++nt)
#pragma unroll
      for (int r = 0; r < 4; ++r) {
        size_t idx = (size_t)(bm + wr + mt * 16 + quad * 4 + r) * N
                     + bn + wc + nt * 16 + l15;
        if (CF32) ((float*)Cv)[idx] = acc[mt][nt][r];
        else      ((ushort*)Cv)[idx] = f2bf(acc[mt][nt][r]);
      }
}

// ------- flash attention, legacy (fallback path) ----------------------------
#define QP 72
#define PP 72

__global__ __launch_bounds__(256) void gqa_attn(
    const ushort* __restrict__ q_buf,  // [B*S, DIM]
    const ushort* __restrict__ k_buf,  // [B*S, 512]
    const ushort* __restrict__ vT,     // [B, 512, S]
    ushort* __restrict__ attn)         // [B*S, DIM]
{
  __shared__ __align__(16) ushort Qs[64 * QP];
  __shared__ __align__(16) ushort Ks[64 * QP];
  __shared__ __align__(16) ushort Vs[64 * QP];
  __shared__ __align__(16) ushort Ps[4][16 * PP];  // wave-private

  int bid = blockIdx.x;
  int qt  = bid & 31;
  int g   = (bid >> 5) & 3;
  int h   = (bid >> 7) & 7;
  int b   = bid >> 10;

  int tid  = threadIdx.x;
  int wave = tid >> 6;
  int lane = tid & 63;
  int l15  = lane & 15;
  int quad = lane >> 4;
  int k8   = quad * 8;

  int srow = tid >> 2;
  int c16  = (tid & 3) * 16;

  {
    const ushort* src = q_buf + (size_t)(b * SEQ + qt * 64 + srow) * DIM
                        + (h * NGRP + g) * HDIM + c16;
    *(uint4*)&Qs[srow * QP + c16]     = *(const uint4*)src;
    *(uint4*)&Qs[srow * QP + c16 + 8] = *(const uint4*)(src + 8);
  }
  __syncthreads();

  bf16x8 bq0 = *(const bf16x8*)&Qs[(wave * 16 + l15) * QP + k8];
  bf16x8 bq1 = *(const bf16x8*)&Qs[(wave * 16 + l15) * QP + 32 + k8];

  float lpart = 0.f;
  floatx4 oarr[4] = {{0,0,0,0},{0,0,0,0},{0,0,0,0},{0,0,0,0}};

  const ushort* kp = k_buf + (size_t)(b * SEQ + srow) * KVDIM + h * HDIM + c16;
  const ushort* vp = vT + ((size_t)(b * NKV + h) * HDIM + srow) * SEQ + c16;

  uint4 kv0 = *(const uint4*)kp;
  uint4 kv1 = *(const uint4*)(kp + 8);
  uint4 vv0 = *(const uint4*)vp;
  uint4 vv1 = *(const uint4*)(vp + 8);

  ushort* Pw = &Ps[wave][0];

  for (int kt = 0; kt < SEQ / 64; ++kt) {
    __syncthreads();
    *(uint4*)&Ks[srow * QP + c16]     = kv0;
    *(uint4*)&Ks[srow * QP + c16 + 8] = kv1;
    *(uint4*)&Vs[srow * QP + c16]     = vv0;
    *(uint4*)&Vs[srow * QP + c16 + 8] = vv1;
    __syncthreads();
    if (kt + 1 < SEQ / 64) {
      kp += (size_t)64 * KVDIM;
      vp += 64;
      kv0 = *(const uint4*)kp;
      kv1 = *(const uint4*)(kp + 8);
      vv0 = *(const uint4*)vp;
      vv1 = *(const uint4*)(vp + 8);
    }

    floatx4 sarr[4];
#pragma unroll
    for (int nt = 0; nt < 4; ++nt) {
      bf16x8 ak0 = *(const bf16x8*)&Ks[(nt * 16 + l15) * QP + k8];
      bf16x8 ak1 = *(const bf16x8*)&Ks[(nt * 16 + l15) * QP + 32 + k8];
      floatx4 s = {0.f, 0.f, 0.f, 0.f};
      s = __builtin_amdgcn_mfma_f32_16x16x32_bf16(ak0, bq0, s, 0, 0, 0);
      s = __builtin_amdgcn_mfma_f32_16x16x32_bf16(ak1, bq1, s, 0, 0, 0);
      sarr[nt] = s;
    }

#pragma unroll
    for (int nt = 0; nt < 4; ++nt) {
      float p0 = __expf(sarr[nt][0] * 0.125f);
      float p1 = __expf(sarr[nt][1] * 0.125f);
      float p2 = __expf(sarr[nt][2] * 0.125f);
      float p3 = __expf(sarr[nt][3] * 0.125f);
      lpart += (p0 + p1) + (p2 + p3);
      uint2 pw;
      pw.x = pack_bf2(p0, p1);
      pw.y = pack_bf2(p2, p3);
      *(uint2*)&Pw[l15 * PP + nt * 16 + quad * 4] = pw;
    }

    bf16x8 ap0 = *(const bf16x8*)&Pw[l15 * PP + k8];
    bf16x8 ap1 = *(const bf16x8*)&Pw[l15 * PP + 32 + k8];
#pragma unroll
    for (int dt = 0; dt < 4; ++dt) {
      bf16x8 bv0q = *(const bf16x8*)&Vs[(dt * 16 + l15) * QP + k8];
      bf16x8 bv1q = *(const bf16x8*)&Vs[(dt * 16 + l15) * QP + 32 + k8];
      oarr[dt] = __builtin_amdgcn_mfma_f32_16x16x32_bf16(ap0, bv0q, oarr[dt], 0, 0, 0);
      oarr[dt] = __builtin_amdgcn_mfma_f32_16x16x32_bf16(ap1, bv1q, oarr[dt], 0, 0, 0);
    }
  }

  float ls = lpart;
  ls += __shfl_xor(ls, 16, 64);
  ls += __shfl_xor(ls, 32, 64);

  __syncthreads();
  float* Lw = (float*)Pw;
  if (quad == 0) Lw[l15] = ls;
  __syncthreads();

#pragma unroll
  for (int r = 0; r < 4; ++r) {
    float inv = 1.0f / Lw[quad * 4 + r];
    int q = qt * 64 + wave * 16 + quad * 4 + r;
    size_t rowoff = (size_t)(b * SEQ + q) * DIM + (h * NGRP + g) * HDIM;
#pragma unroll
    for (int dt = 0; dt < 4; ++dt)
      attn[rowoff + dt * 16 + l15] = f2bf(oarr[dt][r] * inv);
  }
}

// ------- flash attention v3d: g-fused, phase-batched pairs ------------------
// Based on v3c (round 6/10). New: per-slot P buffers (one per g of a pair)
// + phase-batched g-pairs: {A: QK MFMAs for g,g+1} -> {B: exp/pack/store}
// -> fence -> {C: lsum+PV, setprio(1)} -> fence. MFMAs/sarr are register-only
// so the scheduler may overlap pair-1's A-phase with pair-0's B/C — filling
// the dependency-stall gap the round-10 counters exposed (44% VALU, 33% MFMA,
// ~45% neither). Fences drop 8 -> 4 per tile.
__global__ __launch_bounds__(256, 2) void gqa_attn3(
    const ushort* __restrict__ qkv,  // [B*S, 3072] : q[0,2048) k[2048,2560) v[2560,3072)
    const ushort* __restrict__ vT,   // [B, 512, S]
    ushort* __restrict__ attn)       // [B*S, DIM]
{
  __shared__ __align__(16) ushort Ks[64 * QP];        // 9216 B
  __shared__ __align__(16) ushort Vs[64 * QP];        // 9216 B
  __shared__ __align__(16) ushort Ps[4][2][16 * PP];  // 18432 B, wave x slot

  int bid = blockIdx.x;
  int qt  = bid & 31;          // 32 q-tiles of 64 rows
  int h   = (bid >> 5) & 7;
  int b   = bid >> 8;

  int tid  = threadIdx.x;
  int wave = tid >> 6;
  int lane = tid & 63;
  int l15  = lane & 15;
  int quad = lane >> 4;
  int k8   = quad * 8;

  int srow = tid >> 2;
  int c16  = (tid & 3) * 16;

  // Q fragments for all 4 g's, loaded once and pre-scaled by 0.125 (exact)
  bf16x8 bq[NGRP][2];
  {
    const ushort* qrow = qkv + (size_t)(b * SEQ + qt * 64 + wave * 16 + l15) * QKVD
                         + h * NGRP * HDIM;
#pragma unroll
    for (int g = 0; g < NGRP; ++g) {
      bq[g][0] = *(const bf16x8*)(qrow + g * HDIM + k8);
      bq[g][1] = *(const bf16x8*)(qrow + g * HDIM + 32 + k8);
    }
  }
#pragma unroll
  for (int g = 0; g < NGRP; ++g)
#pragma unroll
    for (int j = 0; j < 2; ++j)
#pragma unroll
      for (int e = 0; e < 8; ++e)
        bq[g][j][e] = (__bf16)((float)bq[g][j][e] * 0.125f);

  bf16x8 vones;
#pragma unroll
  for (int i = 0; i < 8; ++i) vones[i] = (__bf16)1.0f;

  floatx4 lacc[NGRP];
  floatx4 oacc[NGRP][4];
#pragma unroll
  for (int g = 0; g < NGRP; ++g) {
    lacc[g] = floatx4{0,0,0,0};
#pragma unroll
    for (int dt = 0; dt < 4; ++dt) oacc[g][dt] = floatx4{0,0,0,0};
  }

  const ushort* kp = qkv + (size_t)(b * SEQ + srow) * QKVD + DIM + h * HDIM + c16;
  const ushort* vp = vT + ((size_t)(b * NKV + h) * HDIM + srow) * SEQ + c16;

  uint4 kv0 = *(const uint4*)kp;
  uint4 kv1 = *(const uint4*)(kp + 8);
  uint4 vv0 = *(const uint4*)vp;
  uint4 vv1 = *(const uint4*)(vp + 8);

  ushort* Pw0 = &Ps[wave][0][0];
  ushort* Pw1 = &Ps[wave][1][0];

  for (int kt = 0; kt < SEQ / 64; ++kt) {
    __syncthreads();
    *(uint4*)&Ks[srow * QP + c16]     = kv0;
    *(uint4*)&Ks[srow * QP + c16 + 8] = kv1;
    *(uint4*)&Vs[srow * QP + c16]     = vv0;
    *(uint4*)&Vs[srow * QP + c16 + 8] = vv1;
    __syncthreads();
    if (kt + 1 < SEQ / 64) {
      kp += (size_t)64 * QKVD;
      vp += 64;
      kv0 = *(const uint4*)kp;
      kv1 = *(const uint4*)(kp + 8);
      vv0 = *(const uint4*)vp;
      vv1 = *(const uint4*)(vp + 8);
    }

    // hoist K/V fragments to registers ONCE per tile (shared by all g)
    bf16x8 ak[4][2], av[4][2];
#pragma unroll
    for (int t = 0; t < 4; ++t) {
      ak[t][0] = *(const bf16x8*)&Ks[(t * 16 + l15) * QP + k8];
      ak[t][1] = *(const bf16x8*)&Ks[(t * 16 + l15) * QP + 32 + k8];
      av[t][0] = *(const bf16x8*)&Vs[(t * 16 + l15) * QP + k8];
      av[t][1] = *(const bf16x8*)&Vs[(t * 16 + l15) * QP + 32 + k8];
    }

#pragma unroll
    for (int gp = 0; gp < 2; ++gp) {   // g pair {2gp, 2gp+1}
      // --- Phase A: QK^T for both g of the pair (16 MFMAs, reg-only out) ---
      floatx4 sarr[2][4];
#pragma unroll
      for (int gg = 0; gg < 2; ++gg) {
        const int g = gp * 2 + gg;
#pragma unroll
        for (int nt = 0; nt < 4; ++nt) {
          floatx4 s = {0.f, 0.f, 0.f, 0.f};
          s = __builtin_amdgcn_mfma_f32_16x16x32_bf16(ak[nt][0], bq[g][0], s, 0, 0, 0);
          s = __builtin_amdgcn_mfma_f32_16x16x32_bf16(ak[nt][1], bq[g][1], s, 0, 0, 0);
          sarr[gg][nt] = s;
        }
      }

      // --- Phase B: exp + pack + P stores (VALU/trans) ---
#pragma unroll
      for (int gg = 0; gg < 2; ++gg) {
        ushort* Pw = gg ? Pw1 : Pw0;
#pragma unroll
        for (int nt = 0; nt < 4; ++nt) {
          float p0 = __expf(sarr[gg][nt][0]);
          float p1 = __expf(sarr[gg][nt][1]);
          float p2 = __expf(sarr[gg][nt][2]);
          float p3 = __expf(sarr[gg][nt][3]);
          uint2 pw;
          pw.x = pack_bf2_rn(p0, p1);
          pw.y = pack_bf2_rn(p2, p3);
          *(uint2*)&Pw[l15 * PP + nt * 16 + quad * 4] = pw;
        }
      }

      // fence: order P writes (uint2) before P reads (bf16x8) — distinct TBAA
      // types; DS is in-order per wave in HW, compiler fence suffices.
      asm volatile("" ::: "memory");

      // --- Phase C: lsum + PV for both g (20 MFMAs, setprio'd cluster) ---
      __builtin_amdgcn_s_setprio(1);
#pragma unroll
      for (int gg = 0; gg < 2; ++gg) {
        const int g = gp * 2 + gg;
        ushort* Pw = gg ? Pw1 : Pw0;
        bf16x8 ap0 = *(const bf16x8*)&Pw[l15 * PP + k8];
        bf16x8 ap1 = *(const bf16x8*)&Pw[l15 * PP + 32 + k8];
        lacc[g] = __builtin_amdgcn_mfma_f32_16x16x32_bf16(ap0, vones, lacc[g], 0, 0, 0);
        lacc[g] = __builtin_amdgcn_mfma_f32_16x16x32_bf16(ap1, vones, lacc[g], 0, 0, 0);
#pragma unroll
        for (int dt = 0; dt < 4; ++dt) {
          oacc[g][dt] = __builtin_amdgcn_mfma_f32_16x16x32_bf16(ap0, av[dt][0], oacc[g][dt], 0, 0, 0);
          oacc[g][dt] = __builtin_amdgcn_mfma_f32_16x16x32_bf16(ap1, av[dt][1], oacc[g][dt], 0, 0, 0);
        }
      }
      __builtin_amdgcn_s_setprio(0);

      // fence: order this pair's P reads before next pair/tile's P writes (WAR)
      asm volatile("" ::: "memory");
    }
  }

  // epilogue: lacc[g][r] = l[q = quad*4+r] in every lane — no cross-lane comm
#pragma unroll
  for (int g = 0; g < NGRP; ++g) {
#pragma unroll
    for (int r = 0; r < 4; ++r) {
      float inv = 1.0f / lacc[g][r];
      int q = qt * 64 + wave * 16 + quad * 4 + r;
      size_t rowoff = (size_t)(b * SEQ + q) * DIM + (h * NGRP + g) * HDIM;
#pragma unroll
      for (int dt = 0; dt < 4; ++dt)
        attn[rowoff + dt * 16 + l15] = f2bf(oacc[g][dt][r] * inv);
    }
  }
}

// ---------------- launch ----------------------------------------------------
extern "C" void kernel_launch(void* const* d_in, const int* in_sizes, int n_in,
                              void* d_out, int out_size, void* d_ws, size_t ws_size,
                              hipStream_t stream)
{
  (void)in_sizes; (void)n_in; (void)out_size;
  const float* x  = (const float*)d_in[0];
  const float* Wq = (const float*)d_in[1];
  const float* Wk = (const float*)d_in[2];
  const float* Wv = (const float*)d_in[3];
  const float* Wo = (const float*)d_in[4];
  float*  outf = (float*)d_out;
  ushort* ob   = (ushort*)d_out;
  ushort* ws16 = (ushort*)d_ws;

  const size_t Mi = 1024 * 1024;
  dim3 blk(256);
  const int M = BATCH * SEQ;

  if (ws_size >= 40u * Mi) {
    // ---- main path: fused QKV projection (+V^T epilogue) + g-fused attn ----
    // ws (Mi ushorts): WqkvT[0,6) = WqT|WkT|WvT as [3072,2048]; WoT[8,12);
    //                  xb[12,20) -> ao[12,20) after projection
    // d_out scratch:   qkv[0,12) = [4096,3072]; vt[12,14)
    ushort* WqkvT = ws16;
    ushort* WoT   = ws16 + 8 * Mi;
    ushort* xb    = ws16 + 12 * Mi;
    ushort* ao    = ws16 + 12 * Mi;   // overlays xb (dead after projection)
    ushort* qkv   = ob;
    ushort* vt    = ob + 12 * Mi;

    // one prep launch: x->bf16 (blocks 0..4095) + all weight transposes
    prep_all<<<dim3(4096 + 2560), blk, 0, stream>>>(x, Wq, Wk, Wv, Wo, xb, WqkvT, WoT);

    // one GEMM for q|k|v; V-region blocks also emit V^T directly into vt
    gemm_lds<false><<<dim3(QKVD / 128, M / 128), blk, 0, stream>>>(
        xb, WqkvT, qkv, vt, M, QKVD, DIM);

    gqa_attn3<<<dim3(BATCH * NKV * (SEQ / 64)), blk, 0, stream>>>(qkv, vt, ao);

    gemm_lds<true><<<dim3(DIM / 128, M / 128), blk, 0, stream>>>(
        ao, WoT, outf, nullptr, M, DIM, DIM);
  } else {
    // ---- fallback: round-4 structure (proven, ws <= 24 MiB) ----
    ushort* qb  = ob;
    ushort* kb  = ob + 8 * Mi;
    ushort* vb  = ob + 10 * Mi;
    ushort* vt  = ob + 12 * Mi;
    ushort* WqT = ws16;
    ushort* WkT = ws16 + 4 * Mi;
    ushort* WvT = ws16 + 5 * Mi;
    ushort* WoT = ws16 + 8 * Mi;
    ushort* ao  = ws16;

    transpose_f2b<<<dim3(DIM / 64,   DIM / 64), blk, 0, stream>>>(Wq, WqT, DIM, DIM);
    transpose_f2b<<<dim3(KVDIM / 64, DIM / 64), blk, 0, stream>>>(Wk, WkT, DIM, KVDIM);
    transpose_f2b<<<dim3(KVDIM / 64, DIM / 64), blk, 0, stream>>>(Wv, WvT, DIM, KVDIM);
    transpose_f2b<<<dim3(DIM / 64,   DIM / 64), blk, 0, stream>>>(Wo, WoT, DIM, DIM);

    gemm128<true, false><<<dim3(DIM / 128, M / 128), blk, 0, stream>>>(x, WqT, qb, M, DIM, DIM);
    gemm_abt<true, false><<<dim3(KVDIM / BN, M / BM), blk, 0, stream>>>(x, WkT, kb, M, KVDIM, DIM);
    gemm_abt<true, false><<<dim3(KVDIM / BN, M / BM), blk, 0, stream>>>(x, WvT, vb, M, KVDIM, DIM);

    transpose_b2b<<<dim3(KVDIM / 64, SEQ / 64, BATCH), blk, 0, stream>>>(
        vb, vt, SEQ, KVDIM, KVDIM, (size_t)SEQ * KVDIM, (size_t)KVDIM * SEQ);

    gqa_attn<<<dim3(BATCH * NKV * NGRP * (SEQ / 64)), blk, 0, stream>>>(qb, kb, vt, ao);

    gemm128<false, true><<<dim3(DIM / 128, M / 128), blk, 0, stream>>>(ao, WoT, outf, M, DIM, DIM);
  }
}